// Round 9
// baseline (578.203 us; speedup 1.0000x reference)
//
#include <hip/hip_runtime.h>
#include <hip/hip_bf16.h>

#define NUM_USERS 100000
#define NUM_ITEMS 50000
#define EMBED     64
#define S_NNZ     (NUM_USERS * 32)
#define R_NNZ     (NUM_USERS * 50)
#define BATCH     8192

// bucket sort parameters: 256 buckets x 391 rows, 256 chunks x 12500 edges
#define NB    256
#define NCH   256
#define CHUNK (S_NNZ / NCH)      // 12500
#define BROWS 391                // 391*256 = 100096 >= NUM_USERS

#define SEGCAP 160               // per-slot R segment capacity (P(deg>160) ~ 1e-30)

// ---------------- two-pass bucket CSR build ----------------

// pass 1a: per-chunk bucket histogram; also fused init of head/bitmap/cntR
__global__ __launch_bounds__(256) void k_p1hist(const int* __restrict__ rows, int* __restrict__ cnt_t,
                                                int* __restrict__ head, unsigned* __restrict__ bitmap,
                                                int* __restrict__ cntR) {
    __shared__ int h[NB];
    int t = threadIdx.x, b = blockIdx.x;
    int gid = b * 256 + t;
    for (int i = gid; i < NUM_USERS; i += NB * 256) head[i] = -1;
    for (int i = gid; i < (NUM_USERS + 31) / 32; i += NB * 256) bitmap[i] = 0;
    for (int i = gid; i < BATCH; i += NB * 256) cntR[i] = 0;
    h[t] = 0;
    __syncthreads();
    int base = b * CHUNK;
    for (int i = t; i < CHUNK; i += 256) atomicAdd(&h[rows[base + i] / BROWS], 1);
    __syncthreads();
    cnt_t[t * NCH + b] = h[t];
}

// flat scan step 1; fused: k_chain (needs head/bitmap init from k_p1hist, prior launch)
__global__ __launch_bounds__(1024) void k_scan1(const int* __restrict__ cnt, int* __restrict__ excl,
                                                int* __restrict__ bsums, int n,
                                                const int* __restrict__ bu, int* __restrict__ head,
                                                int* __restrict__ nxt, unsigned* __restrict__ bitmap) {
    int t = threadIdx.x;
    int i = blockIdx.x * 1024 + t;
    if (i < BATCH) {
        int u = bu[i];
        nxt[i] = atomicExch(&head[u], i);
        atomicOr(&bitmap[u >> 5], 1u << (u & 31));
    }
    __shared__ int buf[1024];
    int x = (i < n) ? cnt[i] : 0;
    buf[t] = x;
    __syncthreads();
    for (int off = 1; off < 1024; off <<= 1) {
        int y = (t >= off) ? buf[t - off] : 0;
        __syncthreads();
        buf[t] += y;
        __syncthreads();
    }
    if (i < n) excl[i] = buf[t] - x;
    if (t == 1023) bsums[blockIdx.x] = buf[1023];
}

__global__ __launch_bounds__(1024) void k_scan2(int* __restrict__ bsums, int nb, int* __restrict__ total_slot) {
    __shared__ int buf[1024];
    int t = threadIdx.x;
    int x = (t < nb) ? bsums[t] : 0;
    buf[t] = x;
    __syncthreads();
    for (int off = 1; off < 1024; off <<= 1) {
        int y = (t >= off) ? buf[t - off] : 0;
        __syncthreads();
        buf[t] += y;
        __syncthreads();
    }
    if (t < nb) bsums[t] = buf[t] - x;
    if (t == 1023) total_slot[0] = buf[1023];
}

__global__ void k_scan3b(int* __restrict__ a, const int* __restrict__ bsums, int n) {
    int i = blockIdx.x * blockDim.x + threadIdx.x;
    if (i < n) a[i] += bsums[i >> 10];
}

// pass 1b scatter; fused: U -> bf16 table convert (grid-stride tail)
__global__ __launch_bounds__(256) void k_p1scatter(const int* __restrict__ rows, const int* __restrict__ cols,
                                                   const float* __restrict__ vals, const int* __restrict__ cnt_t,
                                                   int2* __restrict__ tmpE,
                                                   const float* __restrict__ U, __hip_bfloat16* __restrict__ U16) {
    __shared__ int cur[NB];
    int t = threadIdx.x, b = blockIdx.x;
    cur[t] = cnt_t[t * NCH + b];
    __syncthreads();
    int base = b * CHUNK;
    for (int i = t; i < CHUNK; i += 256) {
        int e  = base + i;
        int r  = rows[e];
        int bk = r / BROWS;
        int pos = atomicAdd(&cur[bk], 1);
        tmpE[pos] = make_int2(((r - bk * BROWS) << 17) | cols[e], __float_as_int(vals[e]));
    }
    const int total = NUM_USERS * EMBED;
    for (int i = b * 256 + t; i < total; i += NB * 256) U16[i] = __float2bfloat16(U[i]);
}

__global__ __launch_bounds__(512) void k_p2(const int2* __restrict__ tmpE, const int* __restrict__ cnt_t,
                                            int* __restrict__ rowptr, int2* __restrict__ colval) {
    __shared__ int h[512];
    __shared__ int s[512];
    __shared__ int cur[512];
    int t = threadIdx.x, k = blockIdx.x;
    int beg = cnt_t[k * NCH];
    int end = (k < NB - 1) ? cnt_t[(k + 1) * NCH] : S_NNZ;
    h[t] = 0;
    __syncthreads();
    for (int j = beg + t; j < end; j += 512) atomicAdd(&h[((unsigned)tmpE[j].x) >> 17], 1);
    __syncthreads();
    s[t] = h[t];
    __syncthreads();
    for (int off = 1; off < 512; off <<= 1) {
        int y = (t >= off) ? s[t - off] : 0;
        __syncthreads();
        s[t] += y;
        __syncthreads();
    }
    int excl = s[t] - h[t];
    int gr   = k * BROWS + t;
    if (t <= BROWS && gr <= NUM_USERS) rowptr[gr] = beg + excl;
    cur[t] = beg + excl;
    __syncthreads();
    for (int j = beg + t; j < end; j += 512) {
        int2 e  = tmpE[j];
        int pos = atomicAdd(&cur[((unsigned)e.x) >> 17], 1);
        colval[pos] = make_int2(e.x & 0x1FFFF, e.y);
    }
}

// ---------------- fused SpMM + dense layer ----------------
// 512 threads = 8 waves; block handles 32 rows (4/wave). W (32KB) swizzled in LDS,
// shared by 8 waves -> LDS 36KB -> 4 blocks/CU = 2048 threads (full occupancy).
// Per row: gather-accumulate (proven k_spmm16 loop), stage [agg|u] in per-wave LDS,
// 128-FMA epilogue (bit-identical order to layer v2), write Uout + Uout16.

__global__ __launch_bounds__(512) void k_spmm_layer(const int* __restrict__ rowptr,
                                                    const int2* __restrict__ colval,
                                                    const __hip_bfloat16* __restrict__ X,
                                                    const float* __restrict__ Uin,
                                                    float* __restrict__ Uout,
                                                    __hip_bfloat16* __restrict__ Uout16,
                                                    const float* __restrict__ W,
                                                    const float* __restrict__ b) {
    __shared__ __align__(16) float Wl[128 * 64];
    __shared__ __align__(16) float xs[8][128];
    int t = threadIdx.x;
    for (int i = t; i < 128 * 64; i += 512) {
        int k = i >> 6, c = i & 63;
        Wl[c * 128 + ((((k >> 2) ^ (c & 7)) << 2) | (k & 3))] = W[i];
    }
    __syncthreads();
    int wv   = t >> 6;           // 0..7
    int lane = t & 63;
    int csw  = lane & 7;
    int cbase = lane * 32;
    const float4* Wt4 = (const float4*)Wl;
    float bias = b[lane];
    int rbase = blockIdx.x * 32 + wv * 4;   // 3125*32 = 100000 exact
#pragma unroll
    for (int q = 0; q < 4; ++q) {
        int row = rbase + q;
        int beg = rowptr[row], end = rowptr[row + 1];
        float acc = 0.0f;
        int j    = beg;
        int jend = beg + ((end - beg) & ~7);
        for (; j < jend; j += 8) {
            int2 cv[8];
#pragma unroll
            for (int u = 0; u < 8; ++u) cv[u] = colval[j + u];
            float x[8];
#pragma unroll
            for (int u = 0; u < 8; ++u) x[u] = __bfloat162float(X[(size_t)cv[u].x * EMBED + lane]);
#pragma unroll
            for (int u = 0; u < 8; ++u) acc = fmaf(__int_as_float(cv[u].y), x[u], acc);
        }
        for (; j < end; ++j)
            acc = fmaf(__int_as_float(colval[j].y), __bfloat162float(X[(size_t)colval[j].x * EMBED + lane]), acc);
        xs[wv][lane]      = acc;
        xs[wv][64 + lane] = Uin[(size_t)row * EMBED + lane];
        const float4* xv = (const float4*)xs[wv];
        float accL = bias;
#pragma unroll 8
        for (int k4 = 0; k4 < 32; ++k4) {
            float4 w4 = Wt4[cbase + (k4 ^ csw)];
            float4 x4 = xv[k4];
            accL = fmaf(x4.x, w4.x, accL); accL = fmaf(x4.y, w4.y, accL);
            accL = fmaf(x4.z, w4.z, accL); accL = fmaf(x4.w, w4.w, accL);
        }
        float v = fmaxf(accL, 0.0f);
        Uout[(size_t)row * EMBED + lane]   = v;
        Uout16[(size_t)row * EMBED + lane] = __float2bfloat16(v);
    }
}

// batch variant: rows via bu[]; epilogue writes out0 u2 part + fused bp/bn gathers
__global__ __launch_bounds__(512) void k_spmm_layer_batch(const int* __restrict__ rowptr,
                                                          const int2* __restrict__ colval,
                                                          const __hip_bfloat16* __restrict__ X,
                                                          const float* __restrict__ Uin,
                                                          const int* __restrict__ bu,
                                                          float* __restrict__ out0,
                                                          const float* __restrict__ W,
                                                          const float* __restrict__ b,
                                                          const float* __restrict__ V,
                                                          const int* __restrict__ bp,
                                                          const int* __restrict__ bn) {
    __shared__ __align__(16) float Wl[128 * 64];
    __shared__ __align__(16) float xs[8][128];
    int t = threadIdx.x;
    for (int i = t; i < 128 * 64; i += 512) {
        int k = i >> 6, c = i & 63;
        Wl[c * 128 + ((((k >> 2) ^ (c & 7)) << 2) | (k & 3))] = W[i];
    }
    __syncthreads();
    int wv   = t >> 6;
    int lane = t & 63;
    int csw  = lane & 7;
    int cbase = lane * 32;
    const float4* Wt4 = (const float4*)Wl;
    float bias = b[lane];
    int sbase = blockIdx.x * 32 + wv * 4;   // 256*32 = 8192 exact
#pragma unroll
    for (int q = 0; q < 4; ++q) {
        int s = sbase + q;
        int r = bu[s];
        int beg = rowptr[r], end = rowptr[r + 1];
        float acc = 0.0f;
        int j    = beg;
        int jend = beg + ((end - beg) & ~7);
        for (; j < jend; j += 8) {
            int2 cv[8];
#pragma unroll
            for (int u = 0; u < 8; ++u) cv[u] = colval[j + u];
            float x[8];
#pragma unroll
            for (int u = 0; u < 8; ++u) x[u] = __bfloat162float(X[(size_t)cv[u].x * EMBED + lane]);
#pragma unroll
            for (int u = 0; u < 8; ++u) acc = fmaf(__int_as_float(cv[u].y), x[u], acc);
        }
        for (; j < end; ++j)
            acc = fmaf(__int_as_float(colval[j].y), __bfloat162float(X[(size_t)colval[j].x * EMBED + lane]), acc);
        xs[wv][lane]      = acc;
        xs[wv][64 + lane] = Uin[(size_t)r * EMBED + lane];
        const float4* xv = (const float4*)xs[wv];
        float accL = bias;
#pragma unroll 8
        for (int k4 = 0; k4 < 32; ++k4) {
            float4 w4 = Wt4[cbase + (k4 ^ csw)];
            float4 x4 = xv[k4];
            accL = fmaf(x4.x, w4.x, accL); accL = fmaf(x4.y, w4.y, accL);
            accL = fmaf(x4.z, w4.z, accL); accL = fmaf(x4.w, w4.w, accL);
        }
        out0[(size_t)s * EMBED + lane] = fmaxf(accL, 0.0f);
        out0[(size_t)(BATCH + s) * EMBED + lane]     = V[(size_t)bp[s] * EMBED + lane];
        out0[(size_t)(2 * BATCH + s) * EMBED + lane] = V[(size_t)bn[s] * EMBED + lane];
    }
}

// ---------------- R handling: bitmap filter -> fixed segments -> register SpMM ----------------

// single 5M-edge pass: bitmap-gated segment fill; also fused V->bf16 convert
__global__ __launch_bounds__(256) void k_rseg(const int* __restrict__ rows,
                                              const int* __restrict__ cols,
                                              const float* __restrict__ vals,
                                              const unsigned* __restrict__ bitmap,
                                              const int* __restrict__ head,
                                              int* __restrict__ cntR,
                                              int2* __restrict__ seg, int nnz,
                                              const float* __restrict__ V,
                                              __hip_bfloat16* __restrict__ V16) {
    int e = blockIdx.x * blockDim.x + threadIdx.x;
    if (e < NUM_ITEMS * EMBED) V16[e] = __float2bfloat16(V[e]);
    if (e >= nnz) return;
    int r = rows[e];
    if (!((bitmap[(unsigned)r >> 5] >> (r & 31)) & 1u)) return;
    int s   = head[r];
    int pos = atomicAdd(&cntR[s], 1);
    if (pos < SEGCAP) seg[s * SEGCAP + pos] = make_int2(cols[e], __float_as_int(vals[e]));
}

// per-chain-head gather SpMM over its segment; write once per slot along chain
__global__ __launch_bounds__(256) void k_rspmm(const int* __restrict__ cntR,
                                               const int2* __restrict__ seg,
                                               const __hip_bfloat16* __restrict__ V16,
                                               const int* __restrict__ bu,
                                               const int* __restrict__ head,
                                               const int* __restrict__ nxt,
                                               float* __restrict__ out0) {
    int s    = blockIdx.x * (blockDim.x >> 6) + (threadIdx.x >> 6);
    int lane = threadIdx.x & 63;
    if (s >= BATCH) return;
    if (head[bu[s]] != s) return;       // only chain heads own edges
    int n = cntR[s];
    if (n > SEGCAP) n = SEGCAP;
    const int2* cv2 = seg + (size_t)s * SEGCAP;
    float acc = 0.0f;
    int j    = 0;
    int jend = n & ~7;
    for (; j < jend; j += 8) {
        int2 cv[8];
#pragma unroll
        for (int u = 0; u < 8; ++u) cv[u] = cv2[j + u];
        float x[8];
#pragma unroll
        for (int u = 0; u < 8; ++u) x[u] = __bfloat162float(V16[(size_t)cv[u].x * EMBED + lane]);
#pragma unroll
        for (int u = 0; u < 8; ++u) acc = fmaf(__int_as_float(cv[u].y), x[u], acc);
    }
    for (; j < n; ++j)
        acc = fmaf(__int_as_float(cv2[j].y), __bfloat162float(V16[(size_t)cv2[j].x * EMBED + lane]), acc);
    int slot = s;
    while (slot >= 0) {
        out0[(size_t)slot * EMBED + lane] += acc;
        slot = nxt[slot];
    }
}

// ---------------- launch ----------------

extern "C" void kernel_launch(void* const* d_in, const int* in_sizes, int n_in,
                              void* d_out, int out_size, void* d_ws, size_t ws_size,
                              hipStream_t stream) {
    const int*   batch_user = (const int*)d_in[0];
    const int*   batch_pos  = (const int*)d_in[1];
    const int*   batch_neg  = (const int*)d_in[2];
    const float* U     = (const float*)d_in[3];
    const float* V     = (const float*)d_in[4];
    const float* W0    = (const float*)d_in[5];
    const float* b0    = (const float*)d_in[6];
    const float* W1    = (const float*)d_in[7];
    const float* b1    = (const float*)d_in[8];
    const int*   S_row = (const int*)d_in[9];
    const int*   S_col = (const int*)d_in[10];
    const float* S_val = (const float*)d_in[11];
    const int*   R_row = (const int*)d_in[12];
    const int*   R_col = (const int*)d_in[13];
    const float* R_val = (const float*)d_in[14];
    float* out = (float*)d_out;

    const size_t tabElems = (size_t)NUM_USERS * EMBED;   // 6.4M

    // workspace layout. Aliases: tmpE <- A (dead before A written by spmm_layer).
    // B region: seg at [0, 10.5MB), A16 at [12.8MB, 25.6MB) — disjoint.
    // X16 holds U16 (from p1scatter) then V16 (from rseg; U16 dead after spmm_layer).
    char* wsb = (char*)d_ws;
    size_t o = 0;
    float* A       = (float*)(wsb + o); o += tabElems * 4;            // U1 fp32 (alias: tmpE)
    float* B       = (float*)(wsb + o); o += tabElems * 4;            // seg + A16
    int*   rowptrS = (int*)(wsb + o);   o += (NUM_USERS + 1) * 4;
    int*   cnt_t   = (int*)(wsb + o);   o += (size_t)NB * NCH * 4;
    int*   bsums   = (int*)(wsb + o);   o += 1024 * 4;
    int*   head    = (int*)(wsb + o);   o += NUM_USERS * 4;
    int*   nxt     = (int*)(wsb + o);   o += BATCH * 4;
    int*   cntR    = (int*)(wsb + o);   o += BATCH * 4;
    unsigned* bitmap = (unsigned*)(wsb + o); o += ((NUM_USERS + 31) / 32) * 4;
    o = (o + 7) & ~(size_t)7;
    int2*  colvalS = (int2*)(wsb + o);  o += (size_t)S_NNZ * 8;
    __hip_bfloat16* X16 = (__hip_bfloat16*)(wsb + o); o += tabElems * 2;

    int2* tmpE = (int2*)A;
    int2* seg  = (int2*)B;                                            // 8192*160*8B = 10.5MB
    __hip_bfloat16* A16 = (__hip_bfloat16*)((char*)B + tabElems * 2); // 12.8MB at +12.8MB

    // ---- CSR of S: two-pass bucket sort (p1hist inits head/bitmap/cntR; scan1 runs chain;
    //      p1scatter converts U->U16) ----
    k_p1hist<<<NCH, 256, 0, stream>>>(S_row, cnt_t, head, bitmap, cntR);
    k_scan1<<<(NB * NCH) / 1024, 1024, 0, stream>>>(cnt_t, cnt_t, bsums, NB * NCH,
                                                    batch_user, head, nxt, bitmap);
    k_scan2<<<1, 1024, 0, stream>>>(bsums, (NB * NCH) / 1024, &bsums[512]);
    k_scan3b<<<(NB * NCH) / 256, 256, 0, stream>>>(cnt_t, bsums, NB * NCH);
    k_p1scatter<<<NCH, 256, 0, stream>>>(S_row, S_col, S_val, cnt_t, tmpE, U, X16);
    k_p2<<<NB, 512, 0, stream>>>(tmpE, cnt_t, rowptrS, colvalS);

    // ---- layer 0 (full, fused): gathers U16, dense W0 epilogue -> A + A16 ----
    k_spmm_layer<<<NUM_USERS / 32, 512, 0, stream>>>(rowptrS, colvalS, X16, U, A, A16, W0, b0);

    // ---- layer 1 (batch, fused): gathers A16, dense W1 epilogue -> out0 u2 + bp/bn ----
    k_spmm_layer_batch<<<BATCH / 32, 512, 0, stream>>>(rowptrS, colvalS, A16, A, batch_user,
                                                       out, W1, b1, V, batch_pos, batch_neg);

    // ---- out0 += (R @ V)[batch rows]: bitmap filter -> segments -> SpMM (cvtV fused) ----
    k_rseg<<<(R_NNZ + 255) / 256, 256, 0, stream>>>(R_row, R_col, R_val, bitmap, head, cntR, seg, R_NNZ,
                                                    V, X16);  // X16 now = V16
    k_rspmm<<<(BATCH * 64 + 255) / 256, 256, 0, stream>>>(cntR, seg, X16, batch_user, head, nxt, out);
}

// Round 10
// 524.101 us; speedup vs baseline: 1.1032x; 1.1032x over previous
//
#include <hip/hip_runtime.h>
#include <hip/hip_bf16.h>

#define NUM_USERS 100000
#define NUM_ITEMS 50000
#define EMBED     64
#define S_NNZ     (NUM_USERS * 32)
#define R_NNZ     (NUM_USERS * 50)
#define BATCH     8192

// bucket sort parameters: 256 buckets x 391 rows, 256 chunks x 12500 edges
#define NB    256
#define NCH   256
#define CHUNK (S_NNZ / NCH)      // 12500
#define BROWS 391                // 391*256 = 100096 >= NUM_USERS

#define SEGCAP 160               // per-slot R segment capacity (P(deg>160) ~ 1e-30)

// ---------------- two-pass bucket CSR build ----------------

// pass 1a: per-chunk bucket histogram; also fused init of head/bitmap/cntR
__global__ __launch_bounds__(256) void k_p1hist(const int* __restrict__ rows, int* __restrict__ cnt_t,
                                                int* __restrict__ head, unsigned* __restrict__ bitmap,
                                                int* __restrict__ cntR) {
    __shared__ int h[NB];
    int t = threadIdx.x, b = blockIdx.x;
    int gid = b * 256 + t;
    for (int i = gid; i < NUM_USERS; i += NB * 256) head[i] = -1;
    for (int i = gid; i < (NUM_USERS + 31) / 32; i += NB * 256) bitmap[i] = 0;
    for (int i = gid; i < BATCH; i += NB * 256) cntR[i] = 0;
    h[t] = 0;
    __syncthreads();
    int base = b * CHUNK;
    for (int i = t; i < CHUNK; i += 256) atomicAdd(&h[rows[base + i] / BROWS], 1);
    __syncthreads();
    cnt_t[t * NCH + b] = h[t];
}

// flat scan step 1; fused: k_chain (head/bitmap init done by k_p1hist, prior launch)
__global__ __launch_bounds__(1024) void k_scan1(const int* __restrict__ cnt, int* __restrict__ excl,
                                                int* __restrict__ bsums, int n,
                                                const int* __restrict__ bu, int* __restrict__ head,
                                                int* __restrict__ nxt, unsigned* __restrict__ bitmap) {
    int t = threadIdx.x;
    int i = blockIdx.x * 1024 + t;
    if (i < BATCH) {
        int u = bu[i];
        nxt[i] = atomicExch(&head[u], i);
        atomicOr(&bitmap[u >> 5], 1u << (u & 31));
    }
    __shared__ int buf[1024];
    int x = (i < n) ? cnt[i] : 0;
    buf[t] = x;
    __syncthreads();
    for (int off = 1; off < 1024; off <<= 1) {
        int y = (t >= off) ? buf[t - off] : 0;
        __syncthreads();
        buf[t] += y;
        __syncthreads();
    }
    if (i < n) excl[i] = buf[t] - x;
    if (t == 1023) bsums[blockIdx.x] = buf[1023];
}

__global__ __launch_bounds__(1024) void k_scan2(int* __restrict__ bsums, int nb, int* __restrict__ total_slot) {
    __shared__ int buf[1024];
    int t = threadIdx.x;
    int x = (t < nb) ? bsums[t] : 0;
    buf[t] = x;
    __syncthreads();
    for (int off = 1; off < 1024; off <<= 1) {
        int y = (t >= off) ? buf[t - off] : 0;
        __syncthreads();
        buf[t] += y;
        __syncthreads();
    }
    if (t < nb) bsums[t] = buf[t] - x;
    if (t == 1023) total_slot[0] = buf[1023];
}

__global__ void k_scan3b(int* __restrict__ a, const int* __restrict__ bsums, int n) {
    int i = blockIdx.x * blockDim.x + threadIdx.x;
    if (i < n) a[i] += bsums[i >> 10];
}

// pass 1b scatter; fused: U -> bf16 table convert (grid-stride tail)
__global__ __launch_bounds__(256) void k_p1scatter(const int* __restrict__ rows, const int* __restrict__ cols,
                                                   const float* __restrict__ vals, const int* __restrict__ cnt_t,
                                                   int2* __restrict__ tmpE,
                                                   const float* __restrict__ U, __hip_bfloat16* __restrict__ U16) {
    __shared__ int cur[NB];
    int t = threadIdx.x, b = blockIdx.x;
    cur[t] = cnt_t[t * NCH + b];
    __syncthreads();
    int base = b * CHUNK;
    for (int i = t; i < CHUNK; i += 256) {
        int e  = base + i;
        int r  = rows[e];
        int bk = r / BROWS;
        int pos = atomicAdd(&cur[bk], 1);
        tmpE[pos] = make_int2(((r - bk * BROWS) << 17) | cols[e], __float_as_int(vals[e]));
    }
    const int total = NUM_USERS * EMBED;
    for (int i = b * 256 + t; i < total; i += NB * 256) U16[i] = __float2bfloat16(U[i]);
}

__global__ __launch_bounds__(512) void k_p2(const int2* __restrict__ tmpE, const int* __restrict__ cnt_t,
                                            int* __restrict__ rowptr, int2* __restrict__ colval) {
    __shared__ int h[512];
    __shared__ int s[512];
    __shared__ int cur[512];
    int t = threadIdx.x, k = blockIdx.x;
    int beg = cnt_t[k * NCH];
    int end = (k < NB - 1) ? cnt_t[(k + 1) * NCH] : S_NNZ;
    h[t] = 0;
    __syncthreads();
    for (int j = beg + t; j < end; j += 512) atomicAdd(&h[((unsigned)tmpE[j].x) >> 17], 1);
    __syncthreads();
    s[t] = h[t];
    __syncthreads();
    for (int off = 1; off < 512; off <<= 1) {
        int y = (t >= off) ? s[t - off] : 0;
        __syncthreads();
        s[t] += y;
        __syncthreads();
    }
    int excl = s[t] - h[t];
    int gr   = k * BROWS + t;
    if (t <= BROWS && gr <= NUM_USERS) rowptr[gr] = beg + excl;
    cur[t] = beg + excl;
    __syncthreads();
    for (int j = beg + t; j < end; j += 512) {
        int2 e  = tmpE[j];
        int pos = atomicAdd(&cur[((unsigned)e.x) >> 17], 1);
        colval[pos] = make_int2(e.x & 0x1FFFF, e.y);
    }
}

// ---------------- SpMM (CSR gather, bf16 table, unroll x8) — proven 104.8us version ----
__global__ __launch_bounds__(256) void k_spmm16(const int* __restrict__ rowptr,
                                                const int2* __restrict__ colval,
                                                const __hip_bfloat16* __restrict__ X,
                                                float* __restrict__ Y, int n_rows) {
    int w    = blockIdx.x * (blockDim.x >> 6) + (threadIdx.x >> 6);
    int lane = threadIdx.x & 63;
    if (w >= n_rows) return;
    int beg = rowptr[w], end = rowptr[w + 1];
    float acc = 0.0f;
    int j    = beg;
    int jend = beg + ((end - beg) & ~7);
    for (; j < jend; j += 8) {
        int2 cv[8];
#pragma unroll
        for (int u = 0; u < 8; ++u) cv[u] = colval[j + u];
        float x[8];
#pragma unroll
        for (int u = 0; u < 8; ++u) x[u] = __bfloat162float(X[(size_t)cv[u].x * EMBED + lane]);
#pragma unroll
        for (int u = 0; u < 8; ++u) acc = fmaf(__int_as_float(cv[u].y), x[u], acc);
    }
    for (; j < end; ++j)
        acc = fmaf(__int_as_float(colval[j].y), __bfloat162float(X[(size_t)colval[j].x * EMBED + lane]), acc);
    Y[(size_t)w * EMBED + lane] = acc;
}

__global__ __launch_bounds__(256) void k_spmm_batch16(const int* __restrict__ rowptr,
                                                      const int2* __restrict__ colval,
                                                      const __hip_bfloat16* __restrict__ X,
                                                      const int* __restrict__ bu,
                                                      float* __restrict__ Agg2, int n) {
    int w    = blockIdx.x * (blockDim.x >> 6) + (threadIdx.x >> 6);
    int lane = threadIdx.x & 63;
    if (w >= n) return;
    int r   = bu[w];
    int beg = rowptr[r], end = rowptr[r + 1];
    float acc = 0.0f;
    int j    = beg;
    int jend = beg + ((end - beg) & ~7);
    for (; j < jend; j += 8) {
        int2 cv[8];
#pragma unroll
        for (int u = 0; u < 8; ++u) cv[u] = colval[j + u];
        float x[8];
#pragma unroll
        for (int u = 0; u < 8; ++u) x[u] = __bfloat162float(X[(size_t)cv[u].x * EMBED + lane]);
#pragma unroll
        for (int u = 0; u < 8; ++u) acc = fmaf(__int_as_float(cv[u].y), x[u], acc);
    }
    for (; j < end; ++j)
        acc = fmaf(__int_as_float(colval[j].y), __bfloat162float(X[(size_t)colval[j].x * EMBED + lane]), acc);
    Agg2[(size_t)w * EMBED + lane] = acc;
}

// ---------------- dense layers (v2, 256-thread, proven) ----------------

__global__ __launch_bounds__(256) void k_layer(const float* __restrict__ Agg,
                                               const float* __restrict__ Uin,
                                               float* __restrict__ Uout,
                                               __hip_bfloat16* __restrict__ Uout16,
                                               const float* __restrict__ W,
                                               const float* __restrict__ b) {
    __shared__ __align__(16) float Wt[64 * 128];
    int t = threadIdx.x;
    for (int i = t; i < 128 * 64; i += 256) {
        int k = i >> 6, c = i & 63;
        Wt[c * 128 + ((((k >> 2) ^ (c & 7)) << 2) | (k & 3))] = W[i];
    }
    int rl = __builtin_amdgcn_readfirstlane(t >> 6);   // wave id 0..3 (wave-uniform)
    int c  = t & 63;
    int rbase = blockIdx.x * 16 + rl * 4;              // 6250*16 = 100000 exact, no guard
    __syncthreads();
    const float4* Wt4 = (const float4*)Wt;
    int  csw   = c & 7;
    int  cbase = c * 32;
    const float4* a0 = (const float4*)(Agg + (size_t)(rbase + 0) * EMBED);
    const float4* a1 = (const float4*)(Agg + (size_t)(rbase + 1) * EMBED);
    const float4* a2 = (const float4*)(Agg + (size_t)(rbase + 2) * EMBED);
    const float4* a3 = (const float4*)(Agg + (size_t)(rbase + 3) * EMBED);
    const float4* u0 = (const float4*)(Uin + (size_t)(rbase + 0) * EMBED);
    const float4* u1 = (const float4*)(Uin + (size_t)(rbase + 1) * EMBED);
    const float4* u2 = (const float4*)(Uin + (size_t)(rbase + 2) * EMBED);
    const float4* u3 = (const float4*)(Uin + (size_t)(rbase + 3) * EMBED);
    float bias = b[c];
    float acc0 = bias, acc1 = bias, acc2 = bias, acc3 = bias;
#pragma unroll 4
    for (int k4 = 0; k4 < 16; ++k4) {
        float4 w4 = Wt4[cbase + (k4 ^ csw)];
        float4 x0 = a0[k4], x1 = a1[k4], x2 = a2[k4], x3 = a3[k4];
        acc0 = fmaf(x0.x, w4.x, acc0); acc0 = fmaf(x0.y, w4.y, acc0); acc0 = fmaf(x0.z, w4.z, acc0); acc0 = fmaf(x0.w, w4.w, acc0);
        acc1 = fmaf(x1.x, w4.x, acc1); acc1 = fmaf(x1.y, w4.y, acc1); acc1 = fmaf(x1.z, w4.z, acc1); acc1 = fmaf(x1.w, w4.w, acc1);
        acc2 = fmaf(x2.x, w4.x, acc2); acc2 = fmaf(x2.y, w4.y, acc2); acc2 = fmaf(x2.z, w4.z, acc2); acc2 = fmaf(x2.w, w4.w, acc2);
        acc3 = fmaf(x3.x, w4.x, acc3); acc3 = fmaf(x3.y, w4.y, acc3); acc3 = fmaf(x3.z, w4.z, acc3); acc3 = fmaf(x3.w, w4.w, acc3);
    }
#pragma unroll 4
    for (int k4 = 16; k4 < 32; ++k4) {
        float4 w4 = Wt4[cbase + (k4 ^ csw)];
        float4 x0 = u0[k4 - 16], x1 = u1[k4 - 16], x2 = u2[k4 - 16], x3 = u3[k4 - 16];
        acc0 = fmaf(x0.x, w4.x, acc0); acc0 = fmaf(x0.y, w4.y, acc0); acc0 = fmaf(x0.z, w4.z, acc0); acc0 = fmaf(x0.w, w4.w, acc0);
        acc1 = fmaf(x1.x, w4.x, acc1); acc1 = fmaf(x1.y, w4.y, acc1); acc1 = fmaf(x1.z, w4.z, acc1); acc1 = fmaf(x1.w, w4.w, acc1);
        acc2 = fmaf(x2.x, w4.x, acc2); acc2 = fmaf(x2.y, w4.y, acc2); acc2 = fmaf(x2.z, w4.z, acc2); acc2 = fmaf(x2.w, w4.w, acc2);
        acc3 = fmaf(x3.x, w4.x, acc3); acc3 = fmaf(x3.y, w4.y, acc3); acc3 = fmaf(x3.z, w4.z, acc3); acc3 = fmaf(x3.w, w4.w, acc3);
    }
    float v0 = fmaxf(acc0, 0.0f), v1 = fmaxf(acc1, 0.0f), v2 = fmaxf(acc2, 0.0f), v3 = fmaxf(acc3, 0.0f);
    Uout[(size_t)(rbase + 0) * EMBED + c] = v0;
    Uout[(size_t)(rbase + 1) * EMBED + c] = v1;
    Uout[(size_t)(rbase + 2) * EMBED + c] = v2;
    Uout[(size_t)(rbase + 3) * EMBED + c] = v3;
    Uout16[(size_t)(rbase + 0) * EMBED + c] = __float2bfloat16(v0);
    Uout16[(size_t)(rbase + 1) * EMBED + c] = __float2bfloat16(v1);
    Uout16[(size_t)(rbase + 2) * EMBED + c] = __float2bfloat16(v2);
    Uout16[(size_t)(rbase + 3) * EMBED + c] = __float2bfloat16(v3);
}

// + fused bp/bn gather epilogue
__global__ __launch_bounds__(256) void k_layer_batch(const float* __restrict__ Agg2,
                                                     const float* __restrict__ Uin,
                                                     const int* __restrict__ bu,
                                                     float* __restrict__ out0,
                                                     const float* __restrict__ W,
                                                     const float* __restrict__ b,
                                                     const float* __restrict__ V,
                                                     const int* __restrict__ bp,
                                                     const int* __restrict__ bn) {
    __shared__ __align__(16) float Wt[64 * 128];
    int t = threadIdx.x;
    for (int i = t; i < 128 * 64; i += 256) {
        int k = i >> 6, c = i & 63;
        Wt[c * 128 + ((((k >> 2) ^ (c & 7)) << 2) | (k & 3))] = W[i];
    }
    int rl = __builtin_amdgcn_readfirstlane(t >> 6);
    int c  = t & 63;
    int sbase = blockIdx.x * 16 + rl * 4;              // 512*16 = 8192 exact
    int r0 = bu[sbase + 0], r1 = bu[sbase + 1], r2 = bu[sbase + 2], r3 = bu[sbase + 3];
    __syncthreads();
    const float4* Wt4 = (const float4*)Wt;
    int  csw   = c & 7;
    int  cbase = c * 32;
    const float4* a0 = (const float4*)(Agg2 + (size_t)(sbase + 0) * EMBED);
    const float4* a1 = (const float4*)(Agg2 + (size_t)(sbase + 1) * EMBED);
    const float4* a2 = (const float4*)(Agg2 + (size_t)(sbase + 2) * EMBED);
    const float4* a3 = (const float4*)(Agg2 + (size_t)(sbase + 3) * EMBED);
    const float4* u0 = (const float4*)(Uin + (size_t)r0 * EMBED);
    const float4* u1 = (const float4*)(Uin + (size_t)r1 * EMBED);
    const float4* u2 = (const float4*)(Uin + (size_t)r2 * EMBED);
    const float4* u3 = (const float4*)(Uin + (size_t)r3 * EMBED);
    float bias = b[c];
    float acc0 = bias, acc1 = bias, acc2 = bias, acc3 = bias;
#pragma unroll 4
    for (int k4 = 0; k4 < 16; ++k4) {
        float4 w4 = Wt4[cbase + (k4 ^ csw)];
        float4 x0 = a0[k4], x1 = a1[k4], x2 = a2[k4], x3 = a3[k4];
        acc0 = fmaf(x0.x, w4.x, acc0); acc0 = fmaf(x0.y, w4.y, acc0); acc0 = fmaf(x0.z, w4.z, acc0); acc0 = fmaf(x0.w, w4.w, acc0);
        acc1 = fmaf(x1.x, w4.x, acc1); acc1 = fmaf(x1.y, w4.y, acc1); acc1 = fmaf(x1.z, w4.z, acc1); acc1 = fmaf(x1.w, w4.w, acc1);
        acc2 = fmaf(x2.x, w4.x, acc2); acc2 = fmaf(x2.y, w4.y, acc2); acc2 = fmaf(x2.z, w4.z, acc2); acc2 = fmaf(x2.w, w4.w, acc2);
        acc3 = fmaf(x3.x, w4.x, acc3); acc3 = fmaf(x3.y, w4.y, acc3); acc3 = fmaf(x3.z, w4.z, acc3); acc3 = fmaf(x3.w, w4.w, acc3);
    }
#pragma unroll 4
    for (int k4 = 16; k4 < 32; ++k4) {
        float4 w4 = Wt4[cbase + (k4 ^ csw)];
        float4 x0 = u0[k4 - 16], x1 = u1[k4 - 16], x2 = u2[k4 - 16], x3 = u3[k4 - 16];
        acc0 = fmaf(x0.x, w4.x, acc0); acc0 = fmaf(x0.y, w4.y, acc0); acc0 = fmaf(x0.z, w4.z, acc0); acc0 = fmaf(x0.w, w4.w, acc0);
        acc1 = fmaf(x1.x, w4.x, acc1); acc1 = fmaf(x1.y, w4.y, acc1); acc1 = fmaf(x1.z, w4.z, acc1); acc1 = fmaf(x1.w, w4.w, acc1);
        acc2 = fmaf(x2.x, w4.x, acc2); acc2 = fmaf(x2.y, w4.y, acc2); acc2 = fmaf(x2.z, w4.z, acc2); acc2 = fmaf(x2.w, w4.w, acc2);
        acc3 = fmaf(x3.x, w4.x, acc3); acc3 = fmaf(x3.y, w4.y, acc3); acc3 = fmaf(x3.z, w4.z, acc3); acc3 = fmaf(x3.w, w4.w, acc3);
    }
    out0[(size_t)(sbase + 0) * EMBED + c] = fmaxf(acc0, 0.0f);
    out0[(size_t)(sbase + 1) * EMBED + c] = fmaxf(acc1, 0.0f);
    out0[(size_t)(sbase + 2) * EMBED + c] = fmaxf(acc2, 0.0f);
    out0[(size_t)(sbase + 3) * EMBED + c] = fmaxf(acc3, 0.0f);
#pragma unroll
    for (int q = 0; q < 4; ++q) {
        int s = sbase + q;
        out0[(size_t)(BATCH + s) * EMBED + c]     = V[(size_t)bp[s] * EMBED + c];
        out0[(size_t)(2 * BATCH + s) * EMBED + c] = V[(size_t)bn[s] * EMBED + c];
    }
}

// ---------------- R handling: bitmap filter -> fixed segments -> register SpMM ----------------

// single 5M-edge pass: bitmap-gated segment fill; also fused V->bf16 convert
__global__ __launch_bounds__(256) void k_rseg(const int* __restrict__ rows,
                                              const int* __restrict__ cols,
                                              const float* __restrict__ vals,
                                              const unsigned* __restrict__ bitmap,
                                              const int* __restrict__ head,
                                              int* __restrict__ cntR,
                                              int2* __restrict__ seg, int nnz,
                                              const float* __restrict__ V,
                                              __hip_bfloat16* __restrict__ V16) {
    int e = blockIdx.x * blockDim.x + threadIdx.x;
    if (e < NUM_ITEMS * EMBED) V16[e] = __float2bfloat16(V[e]);
    if (e >= nnz) return;
    int r = rows[e];
    if (!((bitmap[(unsigned)r >> 5] >> (r & 31)) & 1u)) return;
    int s   = head[r];
    int pos = atomicAdd(&cntR[s], 1);
    if (pos < SEGCAP) seg[s * SEGCAP + pos] = make_int2(cols[e], __float_as_int(vals[e]));
}

// per-chain-head gather SpMM over its segment; write once per slot along chain
__global__ __launch_bounds__(256) void k_rspmm(const int* __restrict__ cntR,
                                               const int2* __restrict__ seg,
                                               const __hip_bfloat16* __restrict__ V16,
                                               const int* __restrict__ bu,
                                               const int* __restrict__ head,
                                               const int* __restrict__ nxt,
                                               float* __restrict__ out0) {
    int s    = blockIdx.x * (blockDim.x >> 6) + (threadIdx.x >> 6);
    int lane = threadIdx.x & 63;
    if (s >= BATCH) return;
    if (head[bu[s]] != s) return;       // only chain heads own edges
    int n = cntR[s];
    if (n > SEGCAP) n = SEGCAP;
    const int2* cv2 = seg + (size_t)s * SEGCAP;
    float acc = 0.0f;
    int j    = 0;
    int jend = n & ~7;
    for (; j < jend; j += 8) {
        int2 cv[8];
#pragma unroll
        for (int u = 0; u < 8; ++u) cv[u] = cv2[j + u];
        float x[8];
#pragma unroll
        for (int u = 0; u < 8; ++u) x[u] = __bfloat162float(V16[(size_t)cv[u].x * EMBED + lane]);
#pragma unroll
        for (int u = 0; u < 8; ++u) acc = fmaf(__int_as_float(cv[u].y), x[u], acc);
    }
    for (; j < n; ++j)
        acc = fmaf(__int_as_float(cv2[j].y), __bfloat162float(V16[(size_t)cv2[j].x * EMBED + lane]), acc);
    int slot = s;
    while (slot >= 0) {
        out0[(size_t)slot * EMBED + lane] += acc;
        slot = nxt[slot];
    }
}

// ---------------- launch ----------------

extern "C" void kernel_launch(void* const* d_in, const int* in_sizes, int n_in,
                              void* d_out, int out_size, void* d_ws, size_t ws_size,
                              hipStream_t stream) {
    const int*   batch_user = (const int*)d_in[0];
    const int*   batch_pos  = (const int*)d_in[1];
    const int*   batch_neg  = (const int*)d_in[2];
    const float* U     = (const float*)d_in[3];
    const float* V     = (const float*)d_in[4];
    const float* W0    = (const float*)d_in[5];
    const float* b0    = (const float*)d_in[6];
    const float* W1    = (const float*)d_in[7];
    const float* b1    = (const float*)d_in[8];
    const int*   S_row = (const int*)d_in[9];
    const int*   S_col = (const int*)d_in[10];
    const float* S_val = (const float*)d_in[11];
    const int*   R_row = (const int*)d_in[12];
    const int*   R_col = (const int*)d_in[13];
    const float* R_val = (const float*)d_in[14];
    float* out = (float*)d_out;

    const size_t tabElems = (size_t)NUM_USERS * EMBED;   // 6.4M

    // workspace layout (round-8 proven). Aliases: tmpE <- A; seg <- B (dead after k_layer).
    // X16 region (12.8 MB) sequentially holds U16 -> A16 -> V16.
    char* wsb = (char*)d_ws;
    size_t o = 0;
    float* A       = (float*)(wsb + o); o += tabElems * 4;            // U1 fp32 (alias: tmpE)
    float* B       = (float*)(wsb + o); o += tabElems * 4;            // agg fp32 (alias: seg)
    float* Agg2    = (float*)(wsb + o); o += (size_t)BATCH * EMBED * 4;
    int*   rowptrS = (int*)(wsb + o);   o += (NUM_USERS + 1) * 4;
    int*   cnt_t   = (int*)(wsb + o);   o += (size_t)NB * NCH * 4;
    int*   bsums   = (int*)(wsb + o);   o += 1024 * 4;
    int*   head    = (int*)(wsb + o);   o += NUM_USERS * 4;
    int*   nxt     = (int*)(wsb + o);   o += BATCH * 4;
    int*   cntR    = (int*)(wsb + o);   o += BATCH * 4;
    unsigned* bitmap = (unsigned*)(wsb + o); o += ((NUM_USERS + 31) / 32) * 4;
    o = (o + 7) & ~(size_t)7;
    int2*  colvalS = (int2*)(wsb + o);  o += (size_t)S_NNZ * 8;
    __hip_bfloat16* X16 = (__hip_bfloat16*)(wsb + o); o += tabElems * 2;

    int2* tmpE = (int2*)A;
    int2* seg  = (int2*)B;   // alias: B dead after k_layer; 8192*160*8B = 10.5MB < 25.6MB

    const int spmm_blocks  = (NUM_USERS * 64 + 255) / 256;
    const int layer_blocks = (NUM_USERS + 15) / 16;

    // ---- CSR of S: two-pass bucket sort (p1hist inits head/bitmap/cntR; scan1 runs chain;
    //      p1scatter converts U->U16) ----
    k_p1hist<<<NCH, 256, 0, stream>>>(S_row, cnt_t, head, bitmap, cntR);
    k_scan1<<<(NB * NCH) / 1024, 1024, 0, stream>>>(cnt_t, cnt_t, bsums, NB * NCH,
                                                    batch_user, head, nxt, bitmap);
    k_scan2<<<1, 1024, 0, stream>>>(bsums, (NB * NCH) / 1024, &bsums[512]);
    k_scan3b<<<(NB * NCH) / 256, 256, 0, stream>>>(cnt_t, bsums, NB * NCH);
    k_p1scatter<<<NCH, 256, 0, stream>>>(S_row, S_col, S_val, cnt_t, tmpE, U, X16);
    k_p2<<<NB, 512, 0, stream>>>(tmpE, cnt_t, rowptrS, colvalS);

    // ---- layer 0 (full): SpMM1 (U16 table), layer v2 (emits A + A16 into X16) ----
    k_spmm16<<<spmm_blocks, 256, 0, stream>>>(rowptrS, colvalS, X16, B, NUM_USERS);
    k_layer<<<layer_blocks, 256, 0, stream>>>(B, U, A, X16, W0, b0);   // X16 now = A16; B dead

    // ---- layer 1 (batch): SpMM2 (A16 table), layer v2 + fused bp/bn gathers ----
    k_spmm_batch16<<<(BATCH * 64 + 255) / 256, 256, 0, stream>>>(rowptrS, colvalS, X16, batch_user, Agg2, BATCH);
    k_layer_batch<<<(BATCH + 15) / 16, 256, 0, stream>>>(Agg2, A, batch_user, out, W1, b1,
                                                         V, batch_pos, batch_neg);  // A dead

    // ---- out0 += (R @ V)[batch rows]: bitmap filter -> segments -> SpMM (cvtV fused) ----
    k_rseg<<<(R_NNZ + 255) / 256, 256, 0, stream>>>(R_row, R_col, R_val, bitmap, head, cntR, seg, R_NNZ,
                                                    V, X16);  // X16 now = V16
    k_rspmm<<<(BATCH * 64 + 255) / 256, 256, 0, stream>>>(cntR, seg, X16, batch_user, head, nxt, out);
}

// Round 11
// 523.387 us; speedup vs baseline: 1.1047x; 1.0014x over previous
//
#include <hip/hip_runtime.h>
#include <hip/hip_bf16.h>

#define NUM_USERS 100000
#define NUM_ITEMS 50000
#define EMBED     64
#define S_NNZ     (NUM_USERS * 32)
#define R_NNZ     (NUM_USERS * 50)
#define BATCH     8192

// bucket sort parameters: 256 buckets x 391 rows, 256 chunks x 12500 edges
#define NB    256
#define NCH   256
#define CHUNK (S_NNZ / NCH)      // 12500
#define BROWS 391                // 391*256 = 100096 >= NUM_USERS

#define SEGCAP 160               // per-slot R segment capacity (P(deg>160) ~ 1e-30)

// ---------------- two-pass bucket CSR build ----------------

// pass 1a: per-chunk bucket histogram; also fused init of head/bitmap/cntR
__global__ __launch_bounds__(256) void k_p1hist(const int* __restrict__ rows, int* __restrict__ cnt_t,
                                                int* __restrict__ head, unsigned* __restrict__ bitmap,
                                                int* __restrict__ cntR) {
    __shared__ int h[NB];
    int t = threadIdx.x, b = blockIdx.x;
    int gid = b * 256 + t;
    for (int i = gid; i < NUM_USERS; i += NB * 256) head[i] = -1;
    for (int i = gid; i < (NUM_USERS + 31) / 32; i += NB * 256) bitmap[i] = 0;
    for (int i = gid; i < BATCH; i += NB * 256) cntR[i] = 0;
    h[t] = 0;
    __syncthreads();
    int base = b * CHUNK;
    for (int i = t; i < CHUNK; i += 256) atomicAdd(&h[rows[base + i] / BROWS], 1);
    __syncthreads();
    cnt_t[t * NCH + b] = h[t];
}

// flat scan step 1; fused: k_chain (head/bitmap init done by k_p1hist, prior launch)
__global__ __launch_bounds__(1024) void k_scan1(const int* __restrict__ cnt, int* __restrict__ excl,
                                                int* __restrict__ bsums, int n,
                                                const int* __restrict__ bu, int* __restrict__ head,
                                                int* __restrict__ nxt, unsigned* __restrict__ bitmap) {
    int t = threadIdx.x;
    int i = blockIdx.x * 1024 + t;
    if (i < BATCH) {
        int u = bu[i];
        nxt[i] = atomicExch(&head[u], i);
        atomicOr(&bitmap[u >> 5], 1u << (u & 31));
    }
    __shared__ int buf[1024];
    int x = (i < n) ? cnt[i] : 0;
    buf[t] = x;
    __syncthreads();
    for (int off = 1; off < 1024; off <<= 1) {
        int y = (t >= off) ? buf[t - off] : 0;
        __syncthreads();
        buf[t] += y;
        __syncthreads();
    }
    if (i < n) excl[i] = buf[t] - x;
    if (t == 1023) bsums[blockIdx.x] = buf[1023];
}

__global__ __launch_bounds__(1024) void k_scan2(int* __restrict__ bsums, int nb, int* __restrict__ total_slot) {
    __shared__ int buf[1024];
    int t = threadIdx.x;
    int x = (t < nb) ? bsums[t] : 0;
    buf[t] = x;
    __syncthreads();
    for (int off = 1; off < 1024; off <<= 1) {
        int y = (t >= off) ? buf[t - off] : 0;
        __syncthreads();
        buf[t] += y;
        __syncthreads();
    }
    if (t < nb) bsums[t] = buf[t] - x;
    if (t == 1023) total_slot[0] = buf[1023];
}

__global__ void k_scan3b(int* __restrict__ a, const int* __restrict__ bsums, int n) {
    int i = blockIdx.x * blockDim.x + threadIdx.x;
    if (i < n) a[i] += bsums[i >> 10];
}

// pass 1b scatter; fused: U -> bf16 table convert (grid-stride tail)
__global__ __launch_bounds__(256) void k_p1scatter(const int* __restrict__ rows, const int* __restrict__ cols,
                                                   const float* __restrict__ vals, const int* __restrict__ cnt_t,
                                                   int2* __restrict__ tmpE,
                                                   const float* __restrict__ U, __hip_bfloat16* __restrict__ U16) {
    __shared__ int cur[NB];
    int t = threadIdx.x, b = blockIdx.x;
    cur[t] = cnt_t[t * NCH + b];
    __syncthreads();
    int base = b * CHUNK;
    for (int i = t; i < CHUNK; i += 256) {
        int e  = base + i;
        int r  = rows[e];
        int bk = r / BROWS;
        int pos = atomicAdd(&cur[bk], 1);
        tmpE[pos] = make_int2(((r - bk * BROWS) << 17) | cols[e], __float_as_int(vals[e]));
    }
    const int total = NUM_USERS * EMBED;
    for (int i = b * 256 + t; i < total; i += NB * 256) U16[i] = __float2bfloat16(U[i]);
}

__global__ __launch_bounds__(512) void k_p2(const int2* __restrict__ tmpE, const int* __restrict__ cnt_t,
                                            int* __restrict__ rowptr, int2* __restrict__ colval) {
    __shared__ int h[512];
    __shared__ int s[512];
    __shared__ int cur[512];
    int t = threadIdx.x, k = blockIdx.x;
    int beg = cnt_t[k * NCH];
    int end = (k < NB - 1) ? cnt_t[(k + 1) * NCH] : S_NNZ;
    h[t] = 0;
    __syncthreads();
    for (int j = beg + t; j < end; j += 512) atomicAdd(&h[((unsigned)tmpE[j].x) >> 17], 1);
    __syncthreads();
    s[t] = h[t];
    __syncthreads();
    for (int off = 1; off < 512; off <<= 1) {
        int y = (t >= off) ? s[t - off] : 0;
        __syncthreads();
        s[t] += y;
        __syncthreads();
    }
    int excl = s[t] - h[t];
    int gr   = k * BROWS + t;
    if (t <= BROWS && gr <= NUM_USERS) rowptr[gr] = beg + excl;
    cur[t] = beg + excl;
    __syncthreads();
    for (int j = beg + t; j < end; j += 512) {
        int2 e  = tmpE[j];
        int pos = atomicAdd(&cur[((unsigned)e.x) >> 17], 1);
        colval[pos] = make_int2(e.x & 0x1FFFF, e.y);
    }
}

// ---------------- SpMM: 2 rows per wave (adjacent CSR runs), 16 outstanding gathers ----
// Per-row FMA order identical to k_spmm16 (bit-exact). Joint loop runs while both rows
// have full 8-blocks; per-row cleanup after. VGPR ~56 (< 64 occupancy cliff).
__global__ __launch_bounds__(256) void k_spmm16p(const int* __restrict__ rowptr,
                                                 const int2* __restrict__ colval,
                                                 const __hip_bfloat16* __restrict__ X,
                                                 float* __restrict__ Y, int n_pairs) {
    int w    = blockIdx.x * (blockDim.x >> 6) + (threadIdx.x >> 6);
    int lane = threadIdx.x & 63;
    if (w >= n_pairs) return;
    int r0   = 2 * w;
    int beg0 = rowptr[r0], mid = rowptr[r0 + 1], end1 = rowptr[r0 + 2];
    float acc0 = 0.0f, acc1 = 0.0f;
    int j0 = beg0, j1 = mid;
    int jend0 = beg0 + ((mid - beg0) & ~7);
    int jend1 = mid + ((end1 - mid) & ~7);
    while (j0 < jend0 && j1 < jend1) {
        int2 ca[8], cb[8];
#pragma unroll
        for (int u = 0; u < 8; ++u) ca[u] = colval[j0 + u];
#pragma unroll
        for (int u = 0; u < 8; ++u) cb[u] = colval[j1 + u];
        float xa[8], xb[8];
#pragma unroll
        for (int u = 0; u < 8; ++u) xa[u] = __bfloat162float(X[(size_t)ca[u].x * EMBED + lane]);
#pragma unroll
        for (int u = 0; u < 8; ++u) xb[u] = __bfloat162float(X[(size_t)cb[u].x * EMBED + lane]);
#pragma unroll
        for (int u = 0; u < 8; ++u) acc0 = fmaf(__int_as_float(ca[u].y), xa[u], acc0);
#pragma unroll
        for (int u = 0; u < 8; ++u) acc1 = fmaf(__int_as_float(cb[u].y), xb[u], acc1);
        j0 += 8; j1 += 8;
    }
    for (; j0 < jend0; j0 += 8) {
        int2 cv[8];
#pragma unroll
        for (int u = 0; u < 8; ++u) cv[u] = colval[j0 + u];
        float x[8];
#pragma unroll
        for (int u = 0; u < 8; ++u) x[u] = __bfloat162float(X[(size_t)cv[u].x * EMBED + lane]);
#pragma unroll
        for (int u = 0; u < 8; ++u) acc0 = fmaf(__int_as_float(cv[u].y), x[u], acc0);
    }
    for (; j1 < jend1; j1 += 8) {
        int2 cv[8];
#pragma unroll
        for (int u = 0; u < 8; ++u) cv[u] = colval[j1 + u];
        float x[8];
#pragma unroll
        for (int u = 0; u < 8; ++u) x[u] = __bfloat162float(X[(size_t)cv[u].x * EMBED + lane]);
#pragma unroll
        for (int u = 0; u < 8; ++u) acc1 = fmaf(__int_as_float(cv[u].y), x[u], acc1);
    }
    for (; j0 < mid; ++j0)
        acc0 = fmaf(__int_as_float(colval[j0].y), __bfloat162float(X[(size_t)colval[j0].x * EMBED + lane]), acc0);
    for (; j1 < end1; ++j1)
        acc1 = fmaf(__int_as_float(colval[j1].y), __bfloat162float(X[(size_t)colval[j1].x * EMBED + lane]), acc1);
    Y[(size_t)r0 * EMBED + lane]       = acc0;
    Y[(size_t)(r0 + 1) * EMBED + lane] = acc1;
}

__global__ __launch_bounds__(256) void k_spmm_batch16(const int* __restrict__ rowptr,
                                                      const int2* __restrict__ colval,
                                                      const __hip_bfloat16* __restrict__ X,
                                                      const int* __restrict__ bu,
                                                      float* __restrict__ Agg2, int n) {
    int w    = blockIdx.x * (blockDim.x >> 6) + (threadIdx.x >> 6);
    int lane = threadIdx.x & 63;
    if (w >= n) return;
    int r   = bu[w];
    int beg = rowptr[r], end = rowptr[r + 1];
    float acc = 0.0f;
    int j    = beg;
    int jend = beg + ((end - beg) & ~7);
    for (; j < jend; j += 8) {
        int2 cv[8];
#pragma unroll
        for (int u = 0; u < 8; ++u) cv[u] = colval[j + u];
        float x[8];
#pragma unroll
        for (int u = 0; u < 8; ++u) x[u] = __bfloat162float(X[(size_t)cv[u].x * EMBED + lane]);
#pragma unroll
        for (int u = 0; u < 8; ++u) acc = fmaf(__int_as_float(cv[u].y), x[u], acc);
    }
    for (; j < end; ++j)
        acc = fmaf(__int_as_float(colval[j].y), __bfloat162float(X[(size_t)colval[j].x * EMBED + lane]), acc);
    Agg2[(size_t)w * EMBED + lane] = acc;
}

// ---------------- dense layers (v2, 256-thread, proven) ----------------

__global__ __launch_bounds__(256) void k_layer(const float* __restrict__ Agg,
                                               const float* __restrict__ Uin,
                                               float* __restrict__ Uout,
                                               __hip_bfloat16* __restrict__ Uout16,
                                               const float* __restrict__ W,
                                               const float* __restrict__ b) {
    __shared__ __align__(16) float Wt[64 * 128];
    int t = threadIdx.x;
    for (int i = t; i < 128 * 64; i += 256) {
        int k = i >> 6, c = i & 63;
        Wt[c * 128 + ((((k >> 2) ^ (c & 7)) << 2) | (k & 3))] = W[i];
    }
    int rl = __builtin_amdgcn_readfirstlane(t >> 6);   // wave id 0..3 (wave-uniform)
    int c  = t & 63;
    int rbase = blockIdx.x * 16 + rl * 4;              // 6250*16 = 100000 exact, no guard
    __syncthreads();
    const float4* Wt4 = (const float4*)Wt;
    int  csw   = c & 7;
    int  cbase = c * 32;
    const float4* a0 = (const float4*)(Agg + (size_t)(rbase + 0) * EMBED);
    const float4* a1 = (const float4*)(Agg + (size_t)(rbase + 1) * EMBED);
    const float4* a2 = (const float4*)(Agg + (size_t)(rbase + 2) * EMBED);
    const float4* a3 = (const float4*)(Agg + (size_t)(rbase + 3) * EMBED);
    const float4* u0 = (const float4*)(Uin + (size_t)(rbase + 0) * EMBED);
    const float4* u1 = (const float4*)(Uin + (size_t)(rbase + 1) * EMBED);
    const float4* u2 = (const float4*)(Uin + (size_t)(rbase + 2) * EMBED);
    const float4* u3 = (const float4*)(Uin + (size_t)(rbase + 3) * EMBED);
    float bias = b[c];
    float acc0 = bias, acc1 = bias, acc2 = bias, acc3 = bias;
#pragma unroll 4
    for (int k4 = 0; k4 < 16; ++k4) {
        float4 w4 = Wt4[cbase + (k4 ^ csw)];
        float4 x0 = a0[k4], x1 = a1[k4], x2 = a2[k4], x3 = a3[k4];
        acc0 = fmaf(x0.x, w4.x, acc0); acc0 = fmaf(x0.y, w4.y, acc0); acc0 = fmaf(x0.z, w4.z, acc0); acc0 = fmaf(x0.w, w4.w, acc0);
        acc1 = fmaf(x1.x, w4.x, acc1); acc1 = fmaf(x1.y, w4.y, acc1); acc1 = fmaf(x1.z, w4.z, acc1); acc1 = fmaf(x1.w, w4.w, acc1);
        acc2 = fmaf(x2.x, w4.x, acc2); acc2 = fmaf(x2.y, w4.y, acc2); acc2 = fmaf(x2.z, w4.z, acc2); acc2 = fmaf(x2.w, w4.w, acc2);
        acc3 = fmaf(x3.x, w4.x, acc3); acc3 = fmaf(x3.y, w4.y, acc3); acc3 = fmaf(x3.z, w4.z, acc3); acc3 = fmaf(x3.w, w4.w, acc3);
    }
#pragma unroll 4
    for (int k4 = 16; k4 < 32; ++k4) {
        float4 w4 = Wt4[cbase + (k4 ^ csw)];
        float4 x0 = u0[k4 - 16], x1 = u1[k4 - 16], x2 = u2[k4 - 16], x3 = u3[k4 - 16];
        acc0 = fmaf(x0.x, w4.x, acc0); acc0 = fmaf(x0.y, w4.y, acc0); acc0 = fmaf(x0.z, w4.z, acc0); acc0 = fmaf(x0.w, w4.w, acc0);
        acc1 = fmaf(x1.x, w4.x, acc1); acc1 = fmaf(x1.y, w4.y, acc1); acc1 = fmaf(x1.z, w4.z, acc1); acc1 = fmaf(x1.w, w4.w, acc1);
        acc2 = fmaf(x2.x, w4.x, acc2); acc2 = fmaf(x2.y, w4.y, acc2); acc2 = fmaf(x2.z, w4.z, acc2); acc2 = fmaf(x2.w, w4.w, acc2);
        acc3 = fmaf(x3.x, w4.x, acc3); acc3 = fmaf(x3.y, w4.y, acc3); acc3 = fmaf(x3.z, w4.z, acc3); acc3 = fmaf(x3.w, w4.w, acc3);
    }
    float v0 = fmaxf(acc0, 0.0f), v1 = fmaxf(acc1, 0.0f), v2 = fmaxf(acc2, 0.0f), v3 = fmaxf(acc3, 0.0f);
    Uout[(size_t)(rbase + 0) * EMBED + c] = v0;
    Uout[(size_t)(rbase + 1) * EMBED + c] = v1;
    Uout[(size_t)(rbase + 2) * EMBED + c] = v2;
    Uout[(size_t)(rbase + 3) * EMBED + c] = v3;
    Uout16[(size_t)(rbase + 0) * EMBED + c] = __float2bfloat16(v0);
    Uout16[(size_t)(rbase + 1) * EMBED + c] = __float2bfloat16(v1);
    Uout16[(size_t)(rbase + 2) * EMBED + c] = __float2bfloat16(v2);
    Uout16[(size_t)(rbase + 3) * EMBED + c] = __float2bfloat16(v3);
}

// + fused bp/bn gather epilogue
__global__ __launch_bounds__(256) void k_layer_batch(const float* __restrict__ Agg2,
                                                     const float* __restrict__ Uin,
                                                     const int* __restrict__ bu,
                                                     float* __restrict__ out0,
                                                     const float* __restrict__ W,
                                                     const float* __restrict__ b,
                                                     const float* __restrict__ V,
                                                     const int* __restrict__ bp,
                                                     const int* __restrict__ bn) {
    __shared__ __align__(16) float Wt[64 * 128];
    int t = threadIdx.x;
    for (int i = t; i < 128 * 64; i += 256) {
        int k = i >> 6, c = i & 63;
        Wt[c * 128 + ((((k >> 2) ^ (c & 7)) << 2) | (k & 3))] = W[i];
    }
    int rl = __builtin_amdgcn_readfirstlane(t >> 6);
    int c  = t & 63;
    int sbase = blockIdx.x * 16 + rl * 4;              // 512*16 = 8192 exact
    int r0 = bu[sbase + 0], r1 = bu[sbase + 1], r2 = bu[sbase + 2], r3 = bu[sbase + 3];
    __syncthreads();
    const float4* Wt4 = (const float4*)Wt;
    int  csw   = c & 7;
    int  cbase = c * 32;
    const float4* a0 = (const float4*)(Agg2 + (size_t)(sbase + 0) * EMBED);
    const float4* a1 = (const float4*)(Agg2 + (size_t)(sbase + 1) * EMBED);
    const float4* a2 = (const float4*)(Agg2 + (size_t)(sbase + 2) * EMBED);
    const float4* a3 = (const float4*)(Agg2 + (size_t)(sbase + 3) * EMBED);
    const float4* u0 = (const float4*)(Uin + (size_t)r0 * EMBED);
    const float4* u1 = (const float4*)(Uin + (size_t)r1 * EMBED);
    const float4* u2 = (const float4*)(Uin + (size_t)r2 * EMBED);
    const float4* u3 = (const float4*)(Uin + (size_t)r3 * EMBED);
    float bias = b[c];
    float acc0 = bias, acc1 = bias, acc2 = bias, acc3 = bias;
#pragma unroll 4
    for (int k4 = 0; k4 < 16; ++k4) {
        float4 w4 = Wt4[cbase + (k4 ^ csw)];
        float4 x0 = a0[k4], x1 = a1[k4], x2 = a2[k4], x3 = a3[k4];
        acc0 = fmaf(x0.x, w4.x, acc0); acc0 = fmaf(x0.y, w4.y, acc0); acc0 = fmaf(x0.z, w4.z, acc0); acc0 = fmaf(x0.w, w4.w, acc0);
        acc1 = fmaf(x1.x, w4.x, acc1); acc1 = fmaf(x1.y, w4.y, acc1); acc1 = fmaf(x1.z, w4.z, acc1); acc1 = fmaf(x1.w, w4.w, acc1);
        acc2 = fmaf(x2.x, w4.x, acc2); acc2 = fmaf(x2.y, w4.y, acc2); acc2 = fmaf(x2.z, w4.z, acc2); acc2 = fmaf(x2.w, w4.w, acc2);
        acc3 = fmaf(x3.x, w4.x, acc3); acc3 = fmaf(x3.y, w4.y, acc3); acc3 = fmaf(x3.z, w4.z, acc3); acc3 = fmaf(x3.w, w4.w, acc3);
    }
#pragma unroll 4
    for (int k4 = 16; k4 < 32; ++k4) {
        float4 w4 = Wt4[cbase + (k4 ^ csw)];
        float4 x0 = u0[k4 - 16], x1 = u1[k4 - 16], x2 = u2[k4 - 16], x3 = u3[k4 - 16];
        acc0 = fmaf(x0.x, w4.x, acc0); acc0 = fmaf(x0.y, w4.y, acc0); acc0 = fmaf(x0.z, w4.z, acc0); acc0 = fmaf(x0.w, w4.w, acc0);
        acc1 = fmaf(x1.x, w4.x, acc1); acc1 = fmaf(x1.y, w4.y, acc1); acc1 = fmaf(x1.z, w4.z, acc1); acc1 = fmaf(x1.w, w4.w, acc1);
        acc2 = fmaf(x2.x, w4.x, acc2); acc2 = fmaf(x2.y, w4.y, acc2); acc2 = fmaf(x2.z, w4.z, acc2); acc2 = fmaf(x2.w, w4.w, acc2);
        acc3 = fmaf(x3.x, w4.x, acc3); acc3 = fmaf(x3.y, w4.y, acc3); acc3 = fmaf(x3.z, w4.z, acc3); acc3 = fmaf(x3.w, w4.w, acc3);
    }
    out0[(size_t)(sbase + 0) * EMBED + c] = fmaxf(acc0, 0.0f);
    out0[(size_t)(sbase + 1) * EMBED + c] = fmaxf(acc1, 0.0f);
    out0[(size_t)(sbase + 2) * EMBED + c] = fmaxf(acc2, 0.0f);
    out0[(size_t)(sbase + 3) * EMBED + c] = fmaxf(acc3, 0.0f);
#pragma unroll
    for (int q = 0; q < 4; ++q) {
        int s = sbase + q;
        out0[(size_t)(BATCH + s) * EMBED + c]     = V[(size_t)bp[s] * EMBED + c];
        out0[(size_t)(2 * BATCH + s) * EMBED + c] = V[(size_t)bn[s] * EMBED + c];
    }
}

// ---------------- R handling: bitmap filter -> fixed segments -> register SpMM ----------------

// single 5M-edge pass: bitmap-gated segment fill; also fused V->bf16 convert
__global__ __launch_bounds__(256) void k_rseg(const int* __restrict__ rows,
                                              const int* __restrict__ cols,
                                              const float* __restrict__ vals,
                                              const unsigned* __restrict__ bitmap,
                                              const int* __restrict__ head,
                                              int* __restrict__ cntR,
                                              int2* __restrict__ seg, int nnz,
                                              const float* __restrict__ V,
                                              __hip_bfloat16* __restrict__ V16) {
    int e = blockIdx.x * blockDim.x + threadIdx.x;
    if (e < NUM_ITEMS * EMBED) V16[e] = __float2bfloat16(V[e]);
    if (e >= nnz) return;
    int r = rows[e];
    if (!((bitmap[(unsigned)r >> 5] >> (r & 31)) & 1u)) return;
    int s   = head[r];
    int pos = atomicAdd(&cntR[s], 1);
    if (pos < SEGCAP) seg[s * SEGCAP + pos] = make_int2(cols[e], __float_as_int(vals[e]));
}

// per-chain-head gather SpMM over its segment; write once per slot along chain
__global__ __launch_bounds__(256) void k_rspmm(const int* __restrict__ cntR,
                                               const int2* __restrict__ seg,
                                               const __hip_bfloat16* __restrict__ V16,
                                               const int* __restrict__ bu,
                                               const int* __restrict__ head,
                                               const int* __restrict__ nxt,
                                               float* __restrict__ out0) {
    int s    = blockIdx.x * (blockDim.x >> 6) + (threadIdx.x >> 6);
    int lane = threadIdx.x & 63;
    if (s >= BATCH) return;
    if (head[bu[s]] != s) return;       // only chain heads own edges
    int n = cntR[s];
    if (n > SEGCAP) n = SEGCAP;
    const int2* cv2 = seg + (size_t)s * SEGCAP;
    float acc = 0.0f;
    int j    = 0;
    int jend = n & ~7;
    for (; j < jend; j += 8) {
        int2 cv[8];
#pragma unroll
        for (int u = 0; u < 8; ++u) cv[u] = cv2[j + u];
        float x[8];
#pragma unroll
        for (int u = 0; u < 8; ++u) x[u] = __bfloat162float(V16[(size_t)cv[u].x * EMBED + lane]);
#pragma unroll
        for (int u = 0; u < 8; ++u) acc = fmaf(__int_as_float(cv[u].y), x[u], acc);
    }
    for (; j < n; ++j)
        acc = fmaf(__int_as_float(cv2[j].y), __bfloat162float(V16[(size_t)cv2[j].x * EMBED + lane]), acc);
    int slot = s;
    while (slot >= 0) {
        out0[(size_t)slot * EMBED + lane] += acc;
        slot = nxt[slot];
    }
}

// ---------------- launch ----------------

extern "C" void kernel_launch(void* const* d_in, const int* in_sizes, int n_in,
                              void* d_out, int out_size, void* d_ws, size_t ws_size,
                              hipStream_t stream) {
    const int*   batch_user = (const int*)d_in[0];
    const int*   batch_pos  = (const int*)d_in[1];
    const int*   batch_neg  = (const int*)d_in[2];
    const float* U     = (const float*)d_in[3];
    const float* V     = (const float*)d_in[4];
    const float* W0    = (const float*)d_in[5];
    const float* b0    = (const float*)d_in[6];
    const float* W1    = (const float*)d_in[7];
    const float* b1    = (const float*)d_in[8];
    const int*   S_row = (const int*)d_in[9];
    const int*   S_col = (const int*)d_in[10];
    const float* S_val = (const float*)d_in[11];
    const int*   R_row = (const int*)d_in[12];
    const int*   R_col = (const int*)d_in[13];
    const float* R_val = (const float*)d_in[14];
    float* out = (float*)d_out;

    const size_t tabElems = (size_t)NUM_USERS * EMBED;   // 6.4M

    // workspace layout (round-8 proven). Aliases: tmpE <- A; seg <- B (dead after k_layer).
    // X16 region (12.8 MB) sequentially holds U16 -> A16 -> V16.
    char* wsb = (char*)d_ws;
    size_t o = 0;
    float* A       = (float*)(wsb + o); o += tabElems * 4;            // U1 fp32 (alias: tmpE)
    float* B       = (float*)(wsb + o); o += tabElems * 4;            // agg fp32 (alias: seg)
    float* Agg2    = (float*)(wsb + o); o += (size_t)BATCH * EMBED * 4;
    int*   rowptrS = (int*)(wsb + o);   o += (NUM_USERS + 1) * 4;
    int*   cnt_t   = (int*)(wsb + o);   o += (size_t)NB * NCH * 4;
    int*   bsums   = (int*)(wsb + o);   o += 1024 * 4;
    int*   head    = (int*)(wsb + o);   o += NUM_USERS * 4;
    int*   nxt     = (int*)(wsb + o);   o += BATCH * 4;
    int*   cntR    = (int*)(wsb + o);   o += BATCH * 4;
    unsigned* bitmap = (unsigned*)(wsb + o); o += ((NUM_USERS + 31) / 32) * 4;
    o = (o + 7) & ~(size_t)7;
    int2*  colvalS = (int2*)(wsb + o);  o += (size_t)S_NNZ * 8;
    __hip_bfloat16* X16 = (__hip_bfloat16*)(wsb + o); o += tabElems * 2;

    int2* tmpE = (int2*)A;
    int2* seg  = (int2*)B;   // alias: B dead after k_layer; 8192*160*8B = 10.5MB < 25.6MB

    const int pair_blocks  = (NUM_USERS / 2) / 4;        // 12500: 2 rows/wave, 4 waves/block
    const int layer_blocks = (NUM_USERS + 15) / 16;

    // ---- CSR of S: two-pass bucket sort (p1hist inits head/bitmap/cntR; scan1 runs chain;
    //      p1scatter converts U->U16) ----
    k_p1hist<<<NCH, 256, 0, stream>>>(S_row, cnt_t, head, bitmap, cntR);
    k_scan1<<<(NB * NCH) / 1024, 1024, 0, stream>>>(cnt_t, cnt_t, bsums, NB * NCH,
                                                    batch_user, head, nxt, bitmap);
    k_scan2<<<1, 1024, 0, stream>>>(bsums, (NB * NCH) / 1024, &bsums[512]);
    k_scan3b<<<(NB * NCH) / 256, 256, 0, stream>>>(cnt_t, bsums, NB * NCH);
    k_p1scatter<<<NCH, 256, 0, stream>>>(S_row, S_col, S_val, cnt_t, tmpE, U, X16);
    k_p2<<<NB, 512, 0, stream>>>(tmpE, cnt_t, rowptrS, colvalS);

    // ---- layer 0 (full): SpMM1 2-rows/wave (U16 table), layer v2 (emits A + A16) ----
    k_spmm16p<<<pair_blocks, 256, 0, stream>>>(rowptrS, colvalS, X16, B, NUM_USERS / 2);
    k_layer<<<layer_blocks, 256, 0, stream>>>(B, U, A, X16, W0, b0);   // X16 now = A16; B dead

    // ---- layer 1 (batch): SpMM2 (A16 table), layer v2 + fused bp/bn gathers ----
    k_spmm_batch16<<<(BATCH * 64 + 255) / 256, 256, 0, stream>>>(rowptrS, colvalS, X16, batch_user, Agg2, BATCH);
    k_layer_batch<<<(BATCH + 15) / 16, 256, 0, stream>>>(Agg2, A, batch_user, out, W1, b1,
                                                         V, batch_pos, batch_neg);  // A dead

    // ---- out0 += (R @ V)[batch rows]: bitmap filter -> segments -> SpMM (cvtV fused) ----
    k_rseg<<<(R_NNZ + 255) / 256, 256, 0, stream>>>(R_row, R_col, R_val, bitmap, head, cntR, seg, R_NNZ,
                                                    V, X16);  // X16 now = V16
    k_rspmm<<<(BATCH * 64 + 255) / 256, 256, 0, stream>>>(cntR, seg, X16, batch_user, head, nxt, out);
}

// Round 12
// 514.115 us; speedup vs baseline: 1.1247x; 1.0180x over previous
//
#include <hip/hip_runtime.h>
#include <hip/hip_bf16.h>

#define NUM_USERS 100000
#define NUM_ITEMS 50000
#define EMBED     64
#define S_NNZ     (NUM_USERS * 32)
#define R_NNZ     (NUM_USERS * 50)
#define BATCH     8192

// bucket sort parameters: 512 buckets x 196 rows, 1024 chunks x 3125 edges
// (NB/NCH raised for build-phase occupancy: p1hist/p1scatter 4 blocks/CU, p2 2/CU)
#define NB    512
#define NCH   1024
#define CHUNK (S_NNZ / NCH)      // 3125
#define BROWS 196                // 196*512 = 100352 >= NUM_USERS

#define SEGCAP 160               // per-slot R segment capacity (P(deg>160) ~ 1e-30)

// ---------------- two-pass bucket CSR build ----------------

// pass 1a: per-chunk bucket histogram; also fused init of head/bitmap/cntR
__global__ __launch_bounds__(256) void k_p1hist(const int* __restrict__ rows, int* __restrict__ cnt_t,
                                                int* __restrict__ head, unsigned* __restrict__ bitmap,
                                                int* __restrict__ cntR) {
    __shared__ int h[NB];
    int t = threadIdx.x, b = blockIdx.x;
    int gid = b * 256 + t;
    for (int i = gid; i < NUM_USERS; i += NCH * 256) head[i] = -1;
    for (int i = gid; i < (NUM_USERS + 31) / 32; i += NCH * 256) bitmap[i] = 0;
    for (int i = gid; i < BATCH; i += NCH * 256) cntR[i] = 0;
    for (int i = t; i < NB; i += 256) h[i] = 0;
    __syncthreads();
    int base = b * CHUNK;
    for (int i = t; i < CHUNK; i += 256) atomicAdd(&h[rows[base + i] / BROWS], 1);
    __syncthreads();
    for (int i = t; i < NB; i += 256) cnt_t[i * NCH + b] = h[i];
}

// flat scan step 1; fused: k_chain (head/bitmap init done by k_p1hist, prior launch)
__global__ __launch_bounds__(1024) void k_scan1(const int* __restrict__ cnt, int* __restrict__ excl,
                                                int* __restrict__ bsums, int n,
                                                const int* __restrict__ bu, int* __restrict__ head,
                                                int* __restrict__ nxt, unsigned* __restrict__ bitmap) {
    int t = threadIdx.x;
    int i = blockIdx.x * 1024 + t;
    if (i < BATCH) {
        int u = bu[i];
        nxt[i] = atomicExch(&head[u], i);
        atomicOr(&bitmap[u >> 5], 1u << (u & 31));
    }
    __shared__ int buf[1024];
    int x = (i < n) ? cnt[i] : 0;
    buf[t] = x;
    __syncthreads();
    for (int off = 1; off < 1024; off <<= 1) {
        int y = (t >= off) ? buf[t - off] : 0;
        __syncthreads();
        buf[t] += y;
        __syncthreads();
    }
    if (i < n) excl[i] = buf[t] - x;
    if (t == 1023) bsums[blockIdx.x] = buf[1023];
}

__global__ __launch_bounds__(1024) void k_scan2(int* __restrict__ bsums, int nb, int* __restrict__ total_slot) {
    __shared__ int buf[1024];
    int t = threadIdx.x;
    int x = (t < nb) ? bsums[t] : 0;
    buf[t] = x;
    __syncthreads();
    for (int off = 1; off < 1024; off <<= 1) {
        int y = (t >= off) ? buf[t - off] : 0;
        __syncthreads();
        buf[t] += y;
        __syncthreads();
    }
    if (t < nb) bsums[t] = buf[t] - x;
    if (t == 1023) total_slot[0] = buf[1023];
}

__global__ void k_scan3b(int* __restrict__ a, const int* __restrict__ bsums, int n) {
    int i = blockIdx.x * blockDim.x + threadIdx.x;
    if (i < n) a[i] += bsums[i >> 10];
}

// pass 1b scatter; fused: U -> bf16 table convert (grid-stride tail)
__global__ __launch_bounds__(256) void k_p1scatter(const int* __restrict__ rows, const int* __restrict__ cols,
                                                   const float* __restrict__ vals, const int* __restrict__ cnt_t,
                                                   int2* __restrict__ tmpE,
                                                   const float* __restrict__ U, __hip_bfloat16* __restrict__ U16) {
    __shared__ int cur[NB];
    int t = threadIdx.x, b = blockIdx.x;
    for (int i = t; i < NB; i += 256) cur[i] = cnt_t[i * NCH + b];
    __syncthreads();
    int base = b * CHUNK;
    for (int i = t; i < CHUNK; i += 256) {
        int e  = base + i;
        int r  = rows[e];
        int bk = r / BROWS;
        int pos = atomicAdd(&cur[bk], 1);
        tmpE[pos] = make_int2(((r - bk * BROWS) << 17) | cols[e], __float_as_int(vals[e]));
    }
    const int total = NUM_USERS * EMBED;
    for (int i = b * 256 + t; i < total; i += NCH * 256) U16[i] = __float2bfloat16(U[i]);
}

__global__ __launch_bounds__(512) void k_p2(const int2* __restrict__ tmpE, const int* __restrict__ cnt_t,
                                            int* __restrict__ rowptr, int2* __restrict__ colval) {
    __shared__ int h[512];
    __shared__ int s[512];
    __shared__ int cur[512];
    int t = threadIdx.x, k = blockIdx.x;
    int beg = cnt_t[k * NCH];
    int end = (k < NB - 1) ? cnt_t[(k + 1) * NCH] : S_NNZ;
    h[t] = 0;
    __syncthreads();
    for (int j = beg + t; j < end; j += 512) atomicAdd(&h[((unsigned)tmpE[j].x) >> 17], 1);
    __syncthreads();
    s[t] = h[t];
    __syncthreads();
    for (int off = 1; off < 512; off <<= 1) {
        int y = (t >= off) ? s[t - off] : 0;
        __syncthreads();
        s[t] += y;
        __syncthreads();
    }
    int excl = s[t] - h[t];
    int gr   = k * BROWS + t;
    if (t <= BROWS && gr <= NUM_USERS) rowptr[gr] = beg + excl;
    cur[t] = beg + excl;
    __syncthreads();
    for (int j = beg + t; j < end; j += 512) {
        int2 e  = tmpE[j];
        int pos = atomicAdd(&cur[((unsigned)e.x) >> 17], 1);
        colval[pos] = make_int2(e.x & 0x1FFFF, e.y);
    }
}

// ---------------- SpMM: 2 rows per wave (adjacent CSR runs), 16 outstanding gathers ----
__global__ __launch_bounds__(256) void k_spmm16p(const int* __restrict__ rowptr,
                                                 const int2* __restrict__ colval,
                                                 const __hip_bfloat16* __restrict__ X,
                                                 float* __restrict__ Y, int n_pairs) {
    int w    = blockIdx.x * (blockDim.x >> 6) + (threadIdx.x >> 6);
    int lane = threadIdx.x & 63;
    if (w >= n_pairs) return;
    int r0   = 2 * w;
    int beg0 = rowptr[r0], mid = rowptr[r0 + 1], end1 = rowptr[r0 + 2];
    float acc0 = 0.0f, acc1 = 0.0f;
    int j0 = beg0, j1 = mid;
    int jend0 = beg0 + ((mid - beg0) & ~7);
    int jend1 = mid + ((end1 - mid) & ~7);
    while (j0 < jend0 && j1 < jend1) {
        int2 ca[8], cb[8];
#pragma unroll
        for (int u = 0; u < 8; ++u) ca[u] = colval[j0 + u];
#pragma unroll
        for (int u = 0; u < 8; ++u) cb[u] = colval[j1 + u];
        float xa[8], xb[8];
#pragma unroll
        for (int u = 0; u < 8; ++u) xa[u] = __bfloat162float(X[(size_t)ca[u].x * EMBED + lane]);
#pragma unroll
        for (int u = 0; u < 8; ++u) xb[u] = __bfloat162float(X[(size_t)cb[u].x * EMBED + lane]);
#pragma unroll
        for (int u = 0; u < 8; ++u) acc0 = fmaf(__int_as_float(ca[u].y), xa[u], acc0);
#pragma unroll
        for (int u = 0; u < 8; ++u) acc1 = fmaf(__int_as_float(cb[u].y), xb[u], acc1);
        j0 += 8; j1 += 8;
    }
    for (; j0 < jend0; j0 += 8) {
        int2 cv[8];
#pragma unroll
        for (int u = 0; u < 8; ++u) cv[u] = colval[j0 + u];
        float x[8];
#pragma unroll
        for (int u = 0; u < 8; ++u) x[u] = __bfloat162float(X[(size_t)cv[u].x * EMBED + lane]);
#pragma unroll
        for (int u = 0; u < 8; ++u) acc0 = fmaf(__int_as_float(cv[u].y), x[u], acc0);
    }
    for (; j1 < jend1; j1 += 8) {
        int2 cv[8];
#pragma unroll
        for (int u = 0; u < 8; ++u) cv[u] = colval[j1 + u];
        float x[8];
#pragma unroll
        for (int u = 0; u < 8; ++u) x[u] = __bfloat162float(X[(size_t)cv[u].x * EMBED + lane]);
#pragma unroll
        for (int u = 0; u < 8; ++u) acc1 = fmaf(__int_as_float(cv[u].y), x[u], acc1);
    }
    for (; j0 < mid; ++j0)
        acc0 = fmaf(__int_as_float(colval[j0].y), __bfloat162float(X[(size_t)colval[j0].x * EMBED + lane]), acc0);
    for (; j1 < end1; ++j1)
        acc1 = fmaf(__int_as_float(colval[j1].y), __bfloat162float(X[(size_t)colval[j1].x * EMBED + lane]), acc1);
    Y[(size_t)r0 * EMBED + lane]       = acc0;
    Y[(size_t)(r0 + 1) * EMBED + lane] = acc1;
}

__global__ __launch_bounds__(256) void k_spmm_batch16(const int* __restrict__ rowptr,
                                                      const int2* __restrict__ colval,
                                                      const __hip_bfloat16* __restrict__ X,
                                                      const int* __restrict__ bu,
                                                      float* __restrict__ Agg2, int n) {
    int w    = blockIdx.x * (blockDim.x >> 6) + (threadIdx.x >> 6);
    int lane = threadIdx.x & 63;
    if (w >= n) return;
    int r   = bu[w];
    int beg = rowptr[r], end = rowptr[r + 1];
    float acc = 0.0f;
    int j    = beg;
    int jend = beg + ((end - beg) & ~7);
    for (; j < jend; j += 8) {
        int2 cv[8];
#pragma unroll
        for (int u = 0; u < 8; ++u) cv[u] = colval[j + u];
        float x[8];
#pragma unroll
        for (int u = 0; u < 8; ++u) x[u] = __bfloat162float(X[(size_t)cv[u].x * EMBED + lane]);
#pragma unroll
        for (int u = 0; u < 8; ++u) acc = fmaf(__int_as_float(cv[u].y), x[u], acc);
    }
    for (; j < end; ++j)
        acc = fmaf(__int_as_float(colval[j].y), __bfloat162float(X[(size_t)colval[j].x * EMBED + lane]), acc);
    Agg2[(size_t)w * EMBED + lane] = acc;
}

// ---------------- dense layers (v2, 256-thread, proven) ----------------

__global__ __launch_bounds__(256) void k_layer(const float* __restrict__ Agg,
                                               const float* __restrict__ Uin,
                                               float* __restrict__ Uout,
                                               __hip_bfloat16* __restrict__ Uout16,
                                               const float* __restrict__ W,
                                               const float* __restrict__ b) {
    __shared__ __align__(16) float Wt[64 * 128];
    int t = threadIdx.x;
    for (int i = t; i < 128 * 64; i += 256) {
        int k = i >> 6, c = i & 63;
        Wt[c * 128 + ((((k >> 2) ^ (c & 7)) << 2) | (k & 3))] = W[i];
    }
    int rl = __builtin_amdgcn_readfirstlane(t >> 6);   // wave id 0..3 (wave-uniform)
    int c  = t & 63;
    int rbase = blockIdx.x * 16 + rl * 4;              // 6250*16 = 100000 exact, no guard
    __syncthreads();
    const float4* Wt4 = (const float4*)Wt;
    int  csw   = c & 7;
    int  cbase = c * 32;
    const float4* a0 = (const float4*)(Agg + (size_t)(rbase + 0) * EMBED);
    const float4* a1 = (const float4*)(Agg + (size_t)(rbase + 1) * EMBED);
    const float4* a2 = (const float4*)(Agg + (size_t)(rbase + 2) * EMBED);
    const float4* a3 = (const float4*)(Agg + (size_t)(rbase + 3) * EMBED);
    const float4* u0 = (const float4*)(Uin + (size_t)(rbase + 0) * EMBED);
    const float4* u1 = (const float4*)(Uin + (size_t)(rbase + 1) * EMBED);
    const float4* u2 = (const float4*)(Uin + (size_t)(rbase + 2) * EMBED);
    const float4* u3 = (const float4*)(Uin + (size_t)(rbase + 3) * EMBED);
    float bias = b[c];
    float acc0 = bias, acc1 = bias, acc2 = bias, acc3 = bias;
#pragma unroll 4
    for (int k4 = 0; k4 < 16; ++k4) {
        float4 w4 = Wt4[cbase + (k4 ^ csw)];
        float4 x0 = a0[k4], x1 = a1[k4], x2 = a2[k4], x3 = a3[k4];
        acc0 = fmaf(x0.x, w4.x, acc0); acc0 = fmaf(x0.y, w4.y, acc0); acc0 = fmaf(x0.z, w4.z, acc0); acc0 = fmaf(x0.w, w4.w, acc0);
        acc1 = fmaf(x1.x, w4.x, acc1); acc1 = fmaf(x1.y, w4.y, acc1); acc1 = fmaf(x1.z, w4.z, acc1); acc1 = fmaf(x1.w, w4.w, acc1);
        acc2 = fmaf(x2.x, w4.x, acc2); acc2 = fmaf(x2.y, w4.y, acc2); acc2 = fmaf(x2.z, w4.z, acc2); acc2 = fmaf(x2.w, w4.w, acc2);
        acc3 = fmaf(x3.x, w4.x, acc3); acc3 = fmaf(x3.y, w4.y, acc3); acc3 = fmaf(x3.z, w4.z, acc3); acc3 = fmaf(x3.w, w4.w, acc3);
    }
#pragma unroll 4
    for (int k4 = 16; k4 < 32; ++k4) {
        float4 w4 = Wt4[cbase + (k4 ^ csw)];
        float4 x0 = u0[k4 - 16], x1 = u1[k4 - 16], x2 = u2[k4 - 16], x3 = u3[k4 - 16];
        acc0 = fmaf(x0.x, w4.x, acc0); acc0 = fmaf(x0.y, w4.y, acc0); acc0 = fmaf(x0.z, w4.z, acc0); acc0 = fmaf(x0.w, w4.w, acc0);
        acc1 = fmaf(x1.x, w4.x, acc1); acc1 = fmaf(x1.y, w4.y, acc1); acc1 = fmaf(x1.z, w4.z, acc1); acc1 = fmaf(x1.w, w4.w, acc1);
        acc2 = fmaf(x2.x, w4.x, acc2); acc2 = fmaf(x2.y, w4.y, acc2); acc2 = fmaf(x2.z, w4.z, acc2); acc2 = fmaf(x2.w, w4.w, acc2);
        acc3 = fmaf(x3.x, w4.x, acc3); acc3 = fmaf(x3.y, w4.y, acc3); acc3 = fmaf(x3.z, w4.z, acc3); acc3 = fmaf(x3.w, w4.w, acc3);
    }
    float v0 = fmaxf(acc0, 0.0f), v1 = fmaxf(acc1, 0.0f), v2 = fmaxf(acc2, 0.0f), v3 = fmaxf(acc3, 0.0f);
    Uout[(size_t)(rbase + 0) * EMBED + c] = v0;
    Uout[(size_t)(rbase + 1) * EMBED + c] = v1;
    Uout[(size_t)(rbase + 2) * EMBED + c] = v2;
    Uout[(size_t)(rbase + 3) * EMBED + c] = v3;
    Uout16[(size_t)(rbase + 0) * EMBED + c] = __float2bfloat16(v0);
    Uout16[(size_t)(rbase + 1) * EMBED + c] = __float2bfloat16(v1);
    Uout16[(size_t)(rbase + 2) * EMBED + c] = __float2bfloat16(v2);
    Uout16[(size_t)(rbase + 3) * EMBED + c] = __float2bfloat16(v3);
}

// + fused bp/bn gather epilogue
__global__ __launch_bounds__(256) void k_layer_batch(const float* __restrict__ Agg2,
                                                     const float* __restrict__ Uin,
                                                     const int* __restrict__ bu,
                                                     float* __restrict__ out0,
                                                     const float* __restrict__ W,
                                                     const float* __restrict__ b,
                                                     const float* __restrict__ V,
                                                     const int* __restrict__ bp,
                                                     const int* __restrict__ bn) {
    __shared__ __align__(16) float Wt[64 * 128];
    int t = threadIdx.x;
    for (int i = t; i < 128 * 64; i += 256) {
        int k = i >> 6, c = i & 63;
        Wt[c * 128 + ((((k >> 2) ^ (c & 7)) << 2) | (k & 3))] = W[i];
    }
    int rl = __builtin_amdgcn_readfirstlane(t >> 6);
    int c  = t & 63;
    int sbase = blockIdx.x * 16 + rl * 4;              // 512*16 = 8192 exact
    int r0 = bu[sbase + 0], r1 = bu[sbase + 1], r2 = bu[sbase + 2], r3 = bu[sbase + 3];
    __syncthreads();
    const float4* Wt4 = (const float4*)Wt;
    int  csw   = c & 7;
    int  cbase = c * 32;
    const float4* a0 = (const float4*)(Agg2 + (size_t)(sbase + 0) * EMBED);
    const float4* a1 = (const float4*)(Agg2 + (size_t)(sbase + 1) * EMBED);
    const float4* a2 = (const float4*)(Agg2 + (size_t)(sbase + 2) * EMBED);
    const float4* a3 = (const float4*)(Agg2 + (size_t)(sbase + 3) * EMBED);
    const float4* u0 = (const float4*)(Uin + (size_t)r0 * EMBED);
    const float4* u1 = (const float4*)(Uin + (size_t)r1 * EMBED);
    const float4* u2 = (const float4*)(Uin + (size_t)r2 * EMBED);
    const float4* u3 = (const float4*)(Uin + (size_t)r3 * EMBED);
    float bias = b[c];
    float acc0 = bias, acc1 = bias, acc2 = bias, acc3 = bias;
#pragma unroll 4
    for (int k4 = 0; k4 < 16; ++k4) {
        float4 w4 = Wt4[cbase + (k4 ^ csw)];
        float4 x0 = a0[k4], x1 = a1[k4], x2 = a2[k4], x3 = a3[k4];
        acc0 = fmaf(x0.x, w4.x, acc0); acc0 = fmaf(x0.y, w4.y, acc0); acc0 = fmaf(x0.z, w4.z, acc0); acc0 = fmaf(x0.w, w4.w, acc0);
        acc1 = fmaf(x1.x, w4.x, acc1); acc1 = fmaf(x1.y, w4.y, acc1); acc1 = fmaf(x1.z, w4.z, acc1); acc1 = fmaf(x1.w, w4.w, acc1);
        acc2 = fmaf(x2.x, w4.x, acc2); acc2 = fmaf(x2.y, w4.y, acc2); acc2 = fmaf(x2.z, w4.z, acc2); acc2 = fmaf(x2.w, w4.w, acc2);
        acc3 = fmaf(x3.x, w4.x, acc3); acc3 = fmaf(x3.y, w4.y, acc3); acc3 = fmaf(x3.z, w4.z, acc3); acc3 = fmaf(x3.w, w4.w, acc3);
    }
#pragma unroll 4
    for (int k4 = 16; k4 < 32; ++k4) {
        float4 w4 = Wt4[cbase + (k4 ^ csw)];
        float4 x0 = u0[k4 - 16], x1 = u1[k4 - 16], x2 = u2[k4 - 16], x3 = u3[k4 - 16];
        acc0 = fmaf(x0.x, w4.x, acc0); acc0 = fmaf(x0.y, w4.y, acc0); acc0 = fmaf(x0.z, w4.z, acc0); acc0 = fmaf(x0.w, w4.w, acc0);
        acc1 = fmaf(x1.x, w4.x, acc1); acc1 = fmaf(x1.y, w4.y, acc1); acc1 = fmaf(x1.z, w4.z, acc1); acc1 = fmaf(x1.w, w4.w, acc1);
        acc2 = fmaf(x2.x, w4.x, acc2); acc2 = fmaf(x2.y, w4.y, acc2); acc2 = fmaf(x2.z, w4.z, acc2); acc2 = fmaf(x2.w, w4.w, acc2);
        acc3 = fmaf(x3.x, w4.x, acc3); acc3 = fmaf(x3.y, w4.y, acc3); acc3 = fmaf(x3.z, w4.z, acc3); acc3 = fmaf(x3.w, w4.w, acc3);
    }
    out0[(size_t)(sbase + 0) * EMBED + c] = fmaxf(acc0, 0.0f);
    out0[(size_t)(sbase + 1) * EMBED + c] = fmaxf(acc1, 0.0f);
    out0[(size_t)(sbase + 2) * EMBED + c] = fmaxf(acc2, 0.0f);
    out0[(size_t)(sbase + 3) * EMBED + c] = fmaxf(acc3, 0.0f);
#pragma unroll
    for (int q = 0; q < 4; ++q) {
        int s = sbase + q;
        out0[(size_t)(BATCH + s) * EMBED + c]     = V[(size_t)bp[s] * EMBED + c];
        out0[(size_t)(2 * BATCH + s) * EMBED + c] = V[(size_t)bn[s] * EMBED + c];
    }
}

// ---------------- R handling: bitmap filter -> fixed segments -> register SpMM ----------------

// single 5M-edge pass: bitmap-gated segment fill; also fused V->bf16 convert
__global__ __launch_bounds__(256) void k_rseg(const int* __restrict__ rows,
                                              const int* __restrict__ cols,
                                              const float* __restrict__ vals,
                                              const unsigned* __restrict__ bitmap,
                                              const int* __restrict__ head,
                                              int* __restrict__ cntR,
                                              int2* __restrict__ seg, int nnz,
                                              const float* __restrict__ V,
                                              __hip_bfloat16* __restrict__ V16) {
    int e = blockIdx.x * blockDim.x + threadIdx.x;
    if (e < NUM_ITEMS * EMBED) V16[e] = __float2bfloat16(V[e]);
    if (e >= nnz) return;
    int r = rows[e];
    if (!((bitmap[(unsigned)r >> 5] >> (r & 31)) & 1u)) return;
    int s   = head[r];
    int pos = atomicAdd(&cntR[s], 1);
    if (pos < SEGCAP) seg[s * SEGCAP + pos] = make_int2(cols[e], __float_as_int(vals[e]));
}

// per-chain-head gather SpMM over its segment; write once per slot along chain
__global__ __launch_bounds__(256) void k_rspmm(const int* __restrict__ cntR,
                                               const int2* __restrict__ seg,
                                               const __hip_bfloat16* __restrict__ V16,
                                               const int* __restrict__ bu,
                                               const int* __restrict__ head,
                                               const int* __restrict__ nxt,
                                               float* __restrict__ out0) {
    int s    = blockIdx.x * (blockDim.x >> 6) + (threadIdx.x >> 6);
    int lane = threadIdx.x & 63;
    if (s >= BATCH) return;
    if (head[bu[s]] != s) return;       // only chain heads own edges
    int n = cntR[s];
    if (n > SEGCAP) n = SEGCAP;
    const int2* cv2 = seg + (size_t)s * SEGCAP;
    float acc = 0.0f;
    int j    = 0;
    int jend = n & ~7;
    for (; j < jend; j += 8) {
        int2 cv[8];
#pragma unroll
        for (int u = 0; u < 8; ++u) cv[u] = cv2[j + u];
        float x[8];
#pragma unroll
        for (int u = 0; u < 8; ++u) x[u] = __bfloat162float(V16[(size_t)cv[u].x * EMBED + lane]);
#pragma unroll
        for (int u = 0; u < 8; ++u) acc = fmaf(__int_as_float(cv[u].y), x[u], acc);
    }
    for (; j < n; ++j)
        acc = fmaf(__int_as_float(cv2[j].y), __bfloat162float(V16[(size_t)cv2[j].x * EMBED + lane]), acc);
    int slot = s;
    while (slot >= 0) {
        out0[(size_t)slot * EMBED + lane] += acc;
        slot = nxt[slot];
    }
}

// ---------------- launch ----------------

extern "C" void kernel_launch(void* const* d_in, const int* in_sizes, int n_in,
                              void* d_out, int out_size, void* d_ws, size_t ws_size,
                              hipStream_t stream) {
    const int*   batch_user = (const int*)d_in[0];
    const int*   batch_pos  = (const int*)d_in[1];
    const int*   batch_neg  = (const int*)d_in[2];
    const float* U     = (const float*)d_in[3];
    const float* V     = (const float*)d_in[4];
    const float* W0    = (const float*)d_in[5];
    const float* b0    = (const float*)d_in[6];
    const float* W1    = (const float*)d_in[7];
    const float* b1    = (const float*)d_in[8];
    const int*   S_row = (const int*)d_in[9];
    const int*   S_col = (const int*)d_in[10];
    const float* S_val = (const float*)d_in[11];
    const int*   R_row = (const int*)d_in[12];
    const int*   R_col = (const int*)d_in[13];
    const float* R_val = (const float*)d_in[14];
    float* out = (float*)d_out;

    const size_t tabElems = (size_t)NUM_USERS * EMBED;   // 6.4M

    // workspace layout. Aliases: tmpE <- A; seg <- B (dead after k_layer).
    // X16 region (12.8 MB) sequentially holds U16 -> A16 -> V16.
    char* wsb = (char*)d_ws;
    size_t o = 0;
    float* A       = (float*)(wsb + o); o += tabElems * 4;            // U1 fp32 (alias: tmpE)
    float* B       = (float*)(wsb + o); o += tabElems * 4;            // agg fp32 (alias: seg)
    float* Agg2    = (float*)(wsb + o); o += (size_t)BATCH * EMBED * 4;
    int*   rowptrS = (int*)(wsb + o);   o += (NUM_USERS + 1) * 4;
    int*   cnt_t   = (int*)(wsb + o);   o += (size_t)NB * NCH * 4;    // 2 MB
    int*   bsums   = (int*)(wsb + o);   o += 1024 * 4;
    int*   head    = (int*)(wsb + o);   o += NUM_USERS * 4;
    int*   nxt     = (int*)(wsb + o);   o += BATCH * 4;
    int*   cntR    = (int*)(wsb + o);   o += BATCH * 4;
    unsigned* bitmap = (unsigned*)(wsb + o); o += ((NUM_USERS + 31) / 32) * 4;
    o = (o + 7) & ~(size_t)7;
    int2*  colvalS = (int2*)(wsb + o);  o += (size_t)S_NNZ * 8;
    __hip_bfloat16* X16 = (__hip_bfloat16*)(wsb + o); o += tabElems * 2;

    int2* tmpE = (int2*)A;
    int2* seg  = (int2*)B;   // alias: B dead after k_layer; 8192*160*8B = 10.5MB < 25.6MB

    const int pair_blocks  = (NUM_USERS / 2) / 4;        // 12500: 2 rows/wave, 4 waves/block
    const int layer_blocks = (NUM_USERS + 15) / 16;

    // ---- CSR of S: two-pass bucket sort, occupancy-raised grids ----
    k_p1hist<<<NCH, 256, 0, stream>>>(S_row, cnt_t, head, bitmap, cntR);
    k_scan1<<<(NB * NCH) / 1024, 1024, 0, stream>>>(cnt_t, cnt_t, bsums, NB * NCH,
                                                    batch_user, head, nxt, bitmap);
    k_scan2<<<1, 1024, 0, stream>>>(bsums, (NB * NCH) / 1024, &bsums[512]);
    k_scan3b<<<(NB * NCH) / 256, 256, 0, stream>>>(cnt_t, bsums, NB * NCH);
    k_p1scatter<<<NCH, 256, 0, stream>>>(S_row, S_col, S_val, cnt_t, tmpE, U, X16);
    k_p2<<<NB, 512, 0, stream>>>(tmpE, cnt_t, rowptrS, colvalS);

    // ---- layer 0 (full): SpMM1 2-rows/wave (U16 table), layer v2 (emits A + A16) ----
    k_spmm16p<<<pair_blocks, 256, 0, stream>>>(rowptrS, colvalS, X16, B, NUM_USERS / 2);
    k_layer<<<layer_blocks, 256, 0, stream>>>(B, U, A, X16, W0, b0);   // X16 now = A16; B dead

    // ---- layer 1 (batch): SpMM2 (A16 table), layer v2 + fused bp/bn gathers ----
    k_spmm_batch16<<<(BATCH * 64 + 255) / 256, 256, 0, stream>>>(rowptrS, colvalS, X16, batch_user, Agg2, BATCH);
    k_layer_batch<<<(BATCH + 15) / 16, 256, 0, stream>>>(Agg2, A, batch_user, out, W1, b1,
                                                         V, batch_pos, batch_neg);  // A dead

    // ---- out0 += (R @ V)[batch rows]: bitmap filter -> segments -> SpMM (cvtV fused) ----
    k_rseg<<<(R_NNZ + 255) / 256, 256, 0, stream>>>(R_row, R_col, R_val, bitmap, head, cntR, seg, R_NNZ,
                                                    V, X16);  // X16 now = V16
    k_rspmm<<<(BATCH * 64 + 255) / 256, 256, 0, stream>>>(cntR, seg, X16, batch_user, head, nxt, out);
}